// Round 2
// baseline (6501.617 us; speedup 1.0000x reference)
//
#include <hip/hip_runtime.h>
#include <hip/hip_bf16.h>

// Problem constants (from reference)
#define LNUM 6
#define BB 16
#define TT 512
#define DD 512
#define HH 8
#define AA 64
#define FFD 2048
#define EE 200000
#define BIASDIM 4

// All float tensors are float32 per the reference (jax default dtype).

// ---------------------------------------------------------------------------
// Embedding + positional encoding: x[b,t,d] = embed[tok]*sqrt(D) + pe[t,d]
// ---------------------------------------------------------------------------
__global__ __launch_bounds__(256) void embed_pe_kernel(
    const int* __restrict__ tokens, const float* __restrict__ embed,
    float* __restrict__ x)
{
    int idx = blockIdx.x * 256 + threadIdx.x;     // < B*T*D
    int d  = idx & (DD - 1);
    int bt = idx >> 9;                             // D = 512
    int t  = bt & (TT - 1);
    int tok = tokens[bt];
    float e = embed[(long long)tok * DD + d] * 22.62741699796952f; // sqrt(512)
    float p = (float)(2 * (d >> 1)) * (1.0f / (float)DD);
    float denom = exp2f(p * 13.287712379549449f);  // 10000^p via log2(10000)
    float angle = (float)t / denom;
    float pe = (d & 1) ? cosf(angle) : sinf(angle);
    x[idx] = e + pe;
}

// ---------------------------------------------------------------------------
// LayerNorm over D=512. One block per row, 256 threads, 2 elements/thread.
// ---------------------------------------------------------------------------
__global__ __launch_bounds__(256) void ln_kernel(
    const float* __restrict__ x, float* __restrict__ y,
    const float* __restrict__ g, const float* __restrict__ b)
{
    long long row = blockIdx.x;
    const float* xr = x + row * DD;
    int tid = threadIdx.x;
    float v0 = xr[tid], v1 = xr[tid + 256];
    float s = v0 + v1, sq = v0 * v0 + v1 * v1;
#pragma unroll
    for (int o = 32; o > 0; o >>= 1) {
        s  += __shfl_down(s, o);
        sq += __shfl_down(sq, o);
    }
    __shared__ float ss[4], sq4[4];
    if ((tid & 63) == 0) { ss[tid >> 6] = s; sq4[tid >> 6] = sq; }
    __syncthreads();
    float st  = ss[0] + ss[1] + ss[2] + ss[3];
    float sqt = sq4[0] + sq4[1] + sq4[2] + sq4[3];
    float mean = st * (1.0f / DD);
    float var  = sqt * (1.0f / DD) - mean * mean;
    float inv  = rsqrtf(var + 1e-3f);
    float y0 = (v0 - mean) * inv * g[tid]       + b[tid];
    float y1 = (v1 - mean) * inv * g[tid + 256] + b[tid + 256];
    y[row * DD + tid]       = y0;
    y[row * DD + tid + 256] = y1;
}

// ---------------------------------------------------------------------------
// ksum[b,t,h] = sum_a k[b,t,h,a]
// ---------------------------------------------------------------------------
__global__ __launch_bounds__(256) void ksum_kernel(
    const float* __restrict__ k, float* __restrict__ ks)
{
    int idx = blockIdx.x * 256 + threadIdx.x;      // < B*T*H
    long long base = (long long)idx * AA;
    float s = 0.f;
#pragma unroll
    for (int a = 0; a < AA; a++) s += k[base + a];
    ks[idx] = s;
}

// ---------------------------------------------------------------------------
// Edge-bias scatter: ev[type] = be[type,:]·bs ; dense[b,q,k] += ev[type]
// ---------------------------------------------------------------------------
__global__ __launch_bounds__(256) void bias_scatter_kernel(
    const int* __restrict__ ab, const float* __restrict__ be,
    const float* __restrict__ bs, float* __restrict__ dense)
{
    __shared__ float ev[BIASDIM];
    int tid = threadIdx.x;
    if (tid < BIASDIM) {
        float s = 0.f;
        for (int a = 0; a < AA; a++) s += be[tid * AA + a] * bs[a];
        ev[tid] = s;
    }
    __syncthreads();
    int e = blockIdx.x * 256 + tid;
    if (e < EE) {
        int ty = ab[e * 4 + 0];
        int b  = ab[e * 4 + 1];
        int q  = ab[e * 4 + 2];
        int kk = ab[e * 4 + 3];
        atomicAdd(&dense[((long long)b * TT + q) * TT + kk], ev[ty]);
    }
}

// ---------------------------------------------------------------------------
// alpha[b,h,q,:] = softmax( (alpha + dense[b,q,:]*ksum[b,:,h]) * rsqrt(A),
//                           masked )
// One block per (b,h,q) row of 512.
// ---------------------------------------------------------------------------
__global__ __launch_bounds__(256) void bias_softmax_kernel(
    float* __restrict__ alpha, const float* __restrict__ dense,
    const float* __restrict__ ks, const float* __restrict__ masks)
{
    int row = blockIdx.x;                          // (b*H + h)*T + q
    int q  = row & (TT - 1);
    int bh = row >> 9;
    int h  = bh & (HH - 1);
    int b  = bh >> 3;
    float* ar = alpha + (long long)row * TT;
    const float* dr = dense + ((long long)b * TT + q) * TT;
    const float* mr = masks + ((long long)b * TT + q) * TT;
    int tid = threadIdx.x;
    float vals[2];
#pragma unroll
    for (int i = 0; i < 2; i++) {
        int kk = tid + i * 256;
        float m = mr[kk];
        float vv = (ar[kk] + dr[kk] * ks[((long long)b * TT + kk) * HH + h]) * 0.125f;
        vv = vv * m + (1.0f - ceilf(m)) * (-3.402823466e38f);
        vals[i] = vv;
    }
    float mx = fmaxf(vals[0], vals[1]);
#pragma unroll
    for (int o = 32; o > 0; o >>= 1) mx = fmaxf(mx, __shfl_down(mx, o));
    __shared__ float sred[4];
    if ((tid & 63) == 0) sred[tid >> 6] = mx;
    __syncthreads();
    mx = fmaxf(fmaxf(sred[0], sred[1]), fmaxf(sred[2], sred[3]));
    __syncthreads();
    float e0 = expf(vals[0] - mx), e1 = expf(vals[1] - mx);
    float s = e0 + e1;
#pragma unroll
    for (int o = 32; o > 0; o >>= 1) s += __shfl_down(s, o);
    if ((tid & 63) == 0) sred[tid >> 6] = s;
    __syncthreads();
    s = sred[0] + sred[1] + sred[2] + sred[3];
    float invs = 1.0f / s;
    ar[tid]       = e0 * invs;
    ar[tid + 256] = e1 * invs;
}

// ---------------------------------------------------------------------------
// Generic tiled GEMM: C[M,N] (+)= A[M,K] @ op(B) (+bias) (relu)
// fp32 accumulate. 64x64 tile, 256 threads, 4x4 micro-tile, BK=16.
// Batched via grid.z with two-level (outer, inner) strides.
// All of M,N multiples of 64 and K multiples of 16 in this problem.
// ---------------------------------------------------------------------------
template <bool TRANSB>
__global__ __launch_bounds__(256) void gemm_tile(
    const float* __restrict__ A, const float* __restrict__ Bp, float* __restrict__ C,
    int M, int N, int K, int lda, int ldb, int ldc,
    int inner, long long sAo, long long sAi, long long sBo, long long sBi,
    long long sCo, long long sCi,
    const float* __restrict__ bias, int accum, int relu)
{
    int z = blockIdx.z;
    int zo = z / inner, zi = z % inner;
    A  += zo * sAo + zi * sAi;
    Bp += zo * sBo + zi * sBi;
    C  += zo * sCo + zi * sCi;

    // +4 pad: store/load aliasing is <=2-way (free on gfx950), rows stay
    // 16B-aligned (68 floats = 272 B, multiple of 16).
    __shared__ __align__(16) float As[16][68];
    __shared__ __align__(16) float Bs[16][68];

    int tid = threadIdx.x;
    int tx = tid & 15, ty = tid >> 4;
    int m0 = blockIdx.x * 64, n0 = blockIdx.y * 64;

    float acc[4][4] = {{0.f, 0.f, 0.f, 0.f}};

    for (int k0 = 0; k0 < K; k0 += 16) {
        {   // A tile
            int kk = tid & 15, r = tid >> 4;
#pragma unroll
            for (int i = 0; i < 4; i++) {
                int m = r + i * 16;
                As[kk][m] = A[(long long)(m0 + m) * lda + (k0 + kk)];
            }
        }
        if (TRANSB) {
            int kk = tid & 15, r = tid >> 4;
#pragma unroll
            for (int i = 0; i < 4; i++) {
                int n = r + i * 16;
                Bs[kk][n] = Bp[(long long)(n0 + n) * ldb + (k0 + kk)];
            }
        } else {
            int nn = tid & 63, kq = tid >> 6;
#pragma unroll
            for (int i = 0; i < 4; i++) {
                int kk = kq + i * 4;
                Bs[kk][nn] = Bp[(long long)(k0 + kk) * ldb + (n0 + nn)];
            }
        }
        __syncthreads();
#pragma unroll
        for (int kk = 0; kk < 16; kk++) {
            float4 av = *(const float4*)&As[kk][ty * 4];
            float4 bv = *(const float4*)&Bs[kk][tx * 4];
            float ar[4] = {av.x, av.y, av.z, av.w};
            float br[4] = {bv.x, bv.y, bv.z, bv.w};
#pragma unroll
            for (int i = 0; i < 4; i++)
#pragma unroll
                for (int j = 0; j < 4; j++)
                    acc[i][j] = fmaf(ar[i], br[j], acc[i][j]);
        }
        __syncthreads();
    }

#pragma unroll
    for (int i = 0; i < 4; i++) {
        int m = m0 + ty * 4 + i;
#pragma unroll
        for (int j = 0; j < 4; j++) {
            int n = n0 + tx * 4 + j;
            float vv = acc[i][j];
            if (bias) vv += bias[n];
            if (accum) vv += C[(long long)m * ldc + n];
            if (relu) vv = fmaxf(vv, 0.f);
            C[(long long)m * ldc + n] = vv;
        }
    }
}

// ---------------------------------------------------------------------------
extern "C" void kernel_launch(void* const* d_in, const int* in_sizes, int n_in,
                              void* d_out, int out_size, void* d_ws, size_t ws_size,
                              hipStream_t stream)
{
    const int*   tokens = (const int*)d_in[0];
    const float* masks  = (const float*)d_in[1];
    const int*   ab     = (const int*)d_in[2];
    const float* embed  = (const float*)d_in[3];
    const float* Wq     = (const float*)d_in[4];
    const float* Wk     = (const float*)d_in[5];
    const float* Wv     = (const float*)d_in[6];
    const float* Wo     = (const float*)d_in[7];
    const float* be     = (const float*)d_in[8];
    const float* bs     = (const float*)d_in[9];
    const float* ln_g   = (const float*)d_in[10];
    const float* ln_b   = (const float*)d_in[11];
    const float* ff1w   = (const float*)d_in[12];
    const float* ff1b   = (const float*)d_in[13];
    const float* ff2w   = (const float*)d_in[14];
    const float* ff2b   = (const float*)d_in[15];
    const float* lng    = (const float*)d_in[16];
    const float* lnb    = (const float*)d_in[17];
    float* out = (float*)d_out;

    const long long NX = (long long)BB * TT * DD;      // 4,194,304
    float* x     = (float*)d_ws;
    float* h     = x + NX;
    float* q     = h + NX;
    float* k     = q + NX;
    float* v     = k + NX;
    float* dense = v + NX;                             // B*T*T
    float* ks    = dense + (long long)BB * TT * TT;    // B*T*H
    float* alpha = ks + (long long)BB * TT * HH;       // B*H*T*T (134 MB)
    float* ffm   = alpha;                              // aliased: FF phase only

    embed_pe_kernel<<<dim3(NX / 256), dim3(256), 0, stream>>>(tokens, embed, x);

    const long long sQKV_b = (long long)TT * HH * AA;  // per-b stride in q/k/v
    const long long sAl_b  = (long long)HH * TT * TT;  // per-b stride in alpha
    const long long sAl_h  = (long long)TT * TT;

    for (int l = 0; l < LNUM; l++) {
        const float* Wq_l  = Wq + (long long)l * DD * HH * AA;
        const float* Wk_l  = Wk + (long long)l * DD * HH * AA;
        const float* Wv_l  = Wv + (long long)l * DD * HH * AA;
        const float* Wo_l  = Wo + (long long)l * HH * AA * DD;
        const float* be_l  = be + (long long)l * BIASDIM * AA;
        const float* bs_l  = bs + (long long)l * AA;
        const float* ff1w_l = ff1w + (long long)l * DD * FFD;
        const float* ff1b_l = ff1b + (long long)l * FFD;
        const float* ff2w_l = ff2w + (long long)l * FFD * DD;
        const float* ff2b_l = ff2b + (long long)l * DD;

        // h = LN(x)
        ln_kernel<<<dim3(BB * TT), dim3(256), 0, stream>>>(
            x, h, ln_g + (l * 2 + 0) * DD, ln_b + (l * 2 + 0) * DD);

        // q/k/v = h @ W
        gemm_tile<false><<<dim3(128, 8, 1), dim3(256), 0, stream>>>(
            h, Wq_l, q, 8192, 512, 512, 512, 512, 512,
            1, 0, 0, 0, 0, 0, 0, nullptr, 0, 0);
        gemm_tile<false><<<dim3(128, 8, 1), dim3(256), 0, stream>>>(
            h, Wk_l, k, 8192, 512, 512, 512, 512, 512,
            1, 0, 0, 0, 0, 0, 0, nullptr, 0, 0);
        gemm_tile<false><<<dim3(128, 8, 1), dim3(256), 0, stream>>>(
            h, Wv_l, v, 8192, 512, 512, 512, 512, 512,
            1, 0, 0, 0, 0, 0, 0, nullptr, 0, 0);

        ksum_kernel<<<dim3(BB * TT * HH / 256), dim3(256), 0, stream>>>(k, ks);

        hipMemsetAsync(dense, 0, sizeof(float) * (size_t)BB * TT * TT, stream);
        bias_scatter_kernel<<<dim3((EE + 255) / 256), dim3(256), 0, stream>>>(
            ab, be_l, bs_l, dense);

        // alpha[b,h] = Q[b,:,h,:] @ K[b,:,h,:]^T
        gemm_tile<true><<<dim3(8, 8, BB * HH), dim3(256), 0, stream>>>(
            q, k, alpha, 512, 512, 64, 512, 512, 512,
            HH, sQKV_b, (long long)AA, sQKV_b, (long long)AA, sAl_b, sAl_h,
            nullptr, 0, 0);

        bias_softmax_kernel<<<dim3(BB * HH * TT), dim3(256), 0, stream>>>(
            alpha, dense, ks, masks);

        // ctx[b,:,h,:] = alpha[b,h] @ V[b,:,h,:]   (written into h)
        gemm_tile<false><<<dim3(8, 1, BB * HH), dim3(256), 0, stream>>>(
            alpha, v, h, 512, 64, 512, 512, 512, 512,
            HH, sAl_b, sAl_h, sQKV_b, (long long)AA, sQKV_b, (long long)AA,
            nullptr, 0, 0);

        // x += ctx @ Wo
        gemm_tile<false><<<dim3(128, 8, 1), dim3(256), 0, stream>>>(
            h, Wo_l, x, 8192, 512, 512, 512, 512, 512,
            1, 0, 0, 0, 0, 0, 0, nullptr, 1, 0);

        // h = LN(x)
        ln_kernel<<<dim3(BB * TT), dim3(256), 0, stream>>>(
            x, h, ln_g + (l * 2 + 1) * DD, ln_b + (l * 2 + 1) * DD);

        // ffm = relu(h @ W1 + b1)
        gemm_tile<false><<<dim3(128, 32, 1), dim3(256), 0, stream>>>(
            h, ff1w_l, ffm, 8192, 2048, 512, 512, 2048, 2048,
            1, 0, 0, 0, 0, 0, 0, ff1b_l, 0, 1);

        // x += ffm @ W2 + b2
        gemm_tile<false><<<dim3(128, 8, 1), dim3(256), 0, stream>>>(
            ffm, ff2w_l, x, 8192, 512, 2048, 2048, 512, 512,
            1, 0, 0, 0, 0, 0, 0, ff2b_l, 1, 0);
    }

    // out = LN(x) with output params
    ln_kernel<<<dim3(BB * TT), dim3(256), 0, stream>>>(x, out, lng, lnb);
}

// Round 3
// 2331.402 us; speedup vs baseline: 2.7887x; 2.7887x over previous
//
#include <hip/hip_runtime.h>
#include <hip/hip_bf16.h>

#define LNUM 6
#define BB 16
#define TT 512
#define DD 512
#define HH 8
#define AA 64
#define FFD 2048
#define EE 200000
#define BIASDIM 4

typedef __bf16 bf16_t;
typedef __attribute__((ext_vector_type(8))) __bf16 bf16x8;
typedef __attribute__((ext_vector_type(4))) float f32x4;

typedef __attribute__((address_space(3))) void lds_void;
typedef const __attribute__((address_space(1))) void glb_void;

__device__ __forceinline__ void async_load16(const bf16_t* g, bf16_t* l) {
    __builtin_amdgcn_global_load_lds((glb_void*)g, (lds_void*)l, 16, 0, 0);
}

// ---------------------------------------------------------------------------
// Embedding + positional encoding (fp32 out)
// ---------------------------------------------------------------------------
__global__ __launch_bounds__(256) void embed_pe_kernel(
    const int* __restrict__ tokens, const float* __restrict__ embed,
    float* __restrict__ x)
{
    int idx = blockIdx.x * 256 + threadIdx.x;
    int d  = idx & (DD - 1);
    int bt = idx >> 9;
    int t  = bt & (TT - 1);
    int tok = tokens[bt];
    float e = embed[(long long)tok * DD + d] * 22.62741699796952f; // sqrt(512)
    float p = (float)(2 * (d >> 1)) * (1.0f / (float)DD);
    float denom = exp2f(p * 13.287712379549449f);  // 10000^p
    float angle = (float)t / denom;
    float pe = (d & 1) ? cosf(angle) : sinf(angle);
    x[idx] = e + pe;
}

// ---------------------------------------------------------------------------
// LayerNorm over D=512, fp32 in, TO out (bf16 for activations, fp32 for final)
// ---------------------------------------------------------------------------
template <typename TO>
__global__ __launch_bounds__(256) void ln_kernel(
    const float* __restrict__ x, TO* __restrict__ y,
    const float* __restrict__ g, const float* __restrict__ b)
{
    long long row = blockIdx.x;
    const float* xr = x + row * DD;
    int tid = threadIdx.x;
    float v0 = xr[tid], v1 = xr[tid + 256];
    float s = v0 + v1, sq = v0 * v0 + v1 * v1;
#pragma unroll
    for (int o = 32; o > 0; o >>= 1) {
        s  += __shfl_down(s, o);
        sq += __shfl_down(sq, o);
    }
    __shared__ float ss[4], sq4[4];
    if ((tid & 63) == 0) { ss[tid >> 6] = s; sq4[tid >> 6] = sq; }
    __syncthreads();
    float st  = ss[0] + ss[1] + ss[2] + ss[3];
    float sqt = sq4[0] + sq4[1] + sq4[2] + sq4[3];
    float mean = st * (1.0f / DD);
    float var  = sqt * (1.0f / DD) - mean * mean;
    float inv  = rsqrtf(var + 1e-3f);
    y[row * DD + tid]       = (TO)((v0 - mean) * inv * g[tid]       + b[tid]);
    y[row * DD + tid + 256] = (TO)((v1 - mean) * inv * g[tid + 256] + b[tid + 256]);
}

// ---------------------------------------------------------------------------
// ksum[b,t,h] = sum_a k_bf[b,t,h,a]
// ---------------------------------------------------------------------------
__global__ __launch_bounds__(256) void ksum_kernel(
    const bf16_t* __restrict__ k, float* __restrict__ ks)
{
    int idx = blockIdx.x * 256 + threadIdx.x;
    long long base = (long long)idx * AA;
    float s = 0.f;
#pragma unroll
    for (int a = 0; a < AA; a++) s += (float)k[base + a];
    ks[idx] = s;
}

// ---------------------------------------------------------------------------
// Edge-bias scatter
// ---------------------------------------------------------------------------
__global__ __launch_bounds__(256) void bias_scatter_kernel(
    const int* __restrict__ ab, const float* __restrict__ be,
    const float* __restrict__ bs, float* __restrict__ dense)
{
    __shared__ float ev[BIASDIM];
    int tid = threadIdx.x;
    if (tid < BIASDIM) {
        float s = 0.f;
        for (int a = 0; a < AA; a++) s += be[tid * AA + a] * bs[a];
        ev[tid] = s;
    }
    __syncthreads();
    int e = blockIdx.x * 256 + tid;
    if (e < EE) {
        int ty = ab[e * 4 + 0];
        int b  = ab[e * 4 + 1];
        int q  = ab[e * 4 + 2];
        int kk = ab[e * 4 + 3];
        atomicAdd(&dense[((long long)b * TT + q) * TT + kk], ev[ty]);
    }
}

// ---------------------------------------------------------------------------
// softmax row: reads fp32 alpha row, writes bf16 IN PLACE (row base, 1024-elt
// stride view). Safe: all reads precede a __syncthreads that precedes writes,
// and each row is owned by exactly one block.
// ---------------------------------------------------------------------------
__global__ __launch_bounds__(256) void bias_softmax_kernel(
    float* __restrict__ alpha, const float* __restrict__ dense,
    const float* __restrict__ ks, const float* __restrict__ masks)
{
    int row = blockIdx.x;                          // (b*H + h)*T + q
    int q  = row & (TT - 1);
    int bh = row >> 9;
    int h  = bh & (HH - 1);
    int b  = bh >> 3;
    float* ar = alpha + (long long)row * TT;
    bf16_t* arb = (bf16_t*)ar;
    const float* dr = dense + ((long long)b * TT + q) * TT;
    const float* mr = masks + ((long long)b * TT + q) * TT;
    int tid = threadIdx.x;
    float vals[2];
#pragma unroll
    for (int i = 0; i < 2; i++) {
        int kk = tid + i * 256;
        float m = mr[kk];
        float vv = (ar[kk] + dr[kk] * ks[((long long)b * TT + kk) * HH + h]) * 0.125f;
        vv = vv * m + (1.0f - ceilf(m)) * (-3.402823466e38f);
        vals[i] = vv;
    }
    float mx = fmaxf(vals[0], vals[1]);
#pragma unroll
    for (int o = 32; o > 0; o >>= 1) mx = fmaxf(mx, __shfl_down(mx, o));
    __shared__ float sred[4];
    if ((tid & 63) == 0) sred[tid >> 6] = mx;
    __syncthreads();
    mx = fmaxf(fmaxf(sred[0], sred[1]), fmaxf(sred[2], sred[3]));
    __syncthreads();
    float e0 = expf(vals[0] - mx), e1 = expf(vals[1] - mx);
    float s = e0 + e1;
#pragma unroll
    for (int o = 32; o > 0; o >>= 1) s += __shfl_down(s, o);
    if ((tid & 63) == 0) sred[tid >> 6] = s;
    __syncthreads();
    s = sred[0] + sred[1] + sred[2] + sred[3];
    float invs = 1.0f / s;
    arb[tid]       = (bf16_t)(e0 * invs);
    arb[tid + 256] = (bf16_t)(e1 * invs);
}

// ---------------------------------------------------------------------------
// Weight convert+transpose: in fp32 [R,Cc] -> out bf16 [Cc,R]. 64x64 tiles.
// ---------------------------------------------------------------------------
__global__ __launch_bounds__(256) void wconv_kernel(
    const float* __restrict__ in, bf16_t* __restrict__ out, int R, int Cc)
{
    __shared__ bf16_t tile[64][65];
    int c0 = blockIdx.x * 64, r0 = blockIdx.y * 64;
    int tid = threadIdx.x;
#pragma unroll
    for (int i = 0; i < 16; i++) {
        int idx = tid + i * 256; int r = idx >> 6, c = idx & 63;
        tile[c][r] = (bf16_t)in[(long long)(r0 + r) * Cc + c0 + c];
    }
    __syncthreads();
#pragma unroll
    for (int i = 0; i < 16; i++) {
        int idx = tid + i * 256; int rr = idx >> 6, cc = idx & 63;
        out[(long long)(c0 + rr) * R + r0 + cc] = tile[rr][cc];
    }
}

struct Ptr4 { const float* p[4]; };

// Same, for the four 512x512 attention weights in one launch (grid.z = 4)
__global__ __launch_bounds__(256) void wconv4_kernel(Ptr4 srcs, bf16_t* __restrict__ out)
{
    __shared__ bf16_t tile[64][65];
    int z = blockIdx.z;
    const float* in = srcs.p[z];
    bf16_t* o = out + (long long)z * DD * DD;
    int c0 = blockIdx.x * 64, r0 = blockIdx.y * 64;
    int tid = threadIdx.x;
#pragma unroll
    for (int i = 0; i < 16; i++) {
        int idx = tid + i * 256; int r = idx >> 6, c = idx & 63;
        tile[c][r] = (bf16_t)in[(long long)(r0 + r) * DD + c0 + c];
    }
    __syncthreads();
#pragma unroll
    for (int i = 0; i < 16; i++) {
        int idx = tid + i * 256; int rr = idx >> 6, cc = idx & 63;
        o[(long long)(c0 + rr) * DD + r0 + cc] = tile[rr][cc];
    }
}

// ---------------------------------------------------------------------------
// v [B,T,H,A] bf16 -> vT [B,H,A,T] bf16
// ---------------------------------------------------------------------------
__global__ __launch_bounds__(256) void vtrans_kernel(
    const bf16_t* __restrict__ v, bf16_t* __restrict__ vT)
{
    __shared__ bf16_t tile[64][65];
    int bh = blockIdx.y; int b = bh >> 3, h = bh & 7;
    int t0 = blockIdx.x * 64;
    int tid = threadIdx.x;
#pragma unroll
    for (int i = 0; i < 16; i++) {
        int idx = tid + i * 256; int r = idx >> 6, c = idx & 63;  // r: t, c: a
        tile[c][r] = v[((long long)(b * TT + t0 + r) * HH + h) * AA + c];
    }
    __syncthreads();
#pragma unroll
    for (int i = 0; i < 16; i++) {
        int idx = tid + i * 256; int a = idx >> 6, t2 = idx & 63;
        vT[(((long long)b * HH + h) * AA + a) * TT + t0 + t2] = tile[a][t2];
    }
}

// ---------------------------------------------------------------------------
// MFMA GEMM: C[M,N] (+)= A[M,K] @ B^T[N,K]^T (+bias)(relu)
// A,B bf16; C TC (float or bf16). BMxBN tile, (BM/64)*(BN/64) waves, each wave
// computes 64x64 via 4x4 of 16x16x32 MFMA. BK=32. global_load_lds staging into
// packed LDS [rows][32] (no padding: wave-uniform base + lane*16 rule).
// Batched: z -> (zo,zi) with two-level strides.
// ---------------------------------------------------------------------------
template <int BM, int BN, typename TC>
__global__ __launch_bounds__((BM / 64) * (BN / 64) * 64) void gemm_mfma(
    const bf16_t* __restrict__ Ag, const bf16_t* __restrict__ Bg, TC* __restrict__ Cg,
    int K, int lda, int ldb, int ldc,
    int inner, long long sAo, long long sAi, long long sBo, long long sBi,
    long long sCo, long long sCi,
    const float* __restrict__ bias, int accum, int relu)
{
    constexpr int WN = BN / 64;
    constexpr int NT = (BM / 64) * (BN / 64) * 64;
    __shared__ __align__(16) bf16_t As[BM * 32];
    __shared__ __align__(16) bf16_t Bs[BN * 32];

    int z = blockIdx.z;
    int zo = z / inner, zi = z - zo * inner;
    Ag += zo * sAo + zi * sAi;
    Bg += zo * sBo + zi * sBi;
    Cg += zo * sCo + zi * sCi;

    int tid = threadIdx.x;
    int wave = tid >> 6, lane = tid & 63;
    int wm = (wave / WN) * 64, wn = (wave % WN) * 64;
    int m0 = blockIdx.x * BM, n0 = blockIdx.y * BN;
    int row16 = lane & 15, quad = lane >> 4;

    f32x4 acc[4][4] = {};

    for (int k0 = 0; k0 < K; k0 += 32) {
#pragma unroll
        for (int p = tid; p < BM * 4; p += NT) {
            int r = p >> 2, c = p & 3;
            async_load16(Ag + (long long)(m0 + r) * lda + k0 + c * 8, As + p * 8);
        }
#pragma unroll
        for (int p = tid; p < BN * 4; p += NT) {
            int r = p >> 2, c = p & 3;
            async_load16(Bg + (long long)(n0 + r) * ldb + k0 + c * 8, Bs + p * 8);
        }
        __syncthreads();
        bf16x8 af[4], bfr[4];
#pragma unroll
        for (int i = 0; i < 4; i++)
            af[i] = *(const bf16x8*)(As + (wm + i * 16 + row16) * 32 + quad * 8);
#pragma unroll
        for (int j = 0; j < 4; j++)
            bfr[j] = *(const bf16x8*)(Bs + (wn + j * 16 + row16) * 32 + quad * 8);
#pragma unroll
        for (int i = 0; i < 4; i++)
#pragma unroll
            for (int j = 0; j < 4; j++)
                acc[i][j] = __builtin_amdgcn_mfma_f32_16x16x32_bf16(
                    af[i], bfr[j], acc[i][j], 0, 0, 0);
        __syncthreads();
    }

#pragma unroll
    for (int i = 0; i < 4; i++) {
#pragma unroll
        for (int j = 0; j < 4; j++) {
#pragma unroll
            for (int r = 0; r < 4; r++) {
                int m = m0 + wm + i * 16 + quad * 4 + r;
                int n = n0 + wn + j * 16 + row16;
                float vv = acc[i][j][r];
                if (bias) vv += bias[n];
                if (accum) vv += (float)Cg[(long long)m * ldc + n];
                if (relu) vv = fmaxf(vv, 0.f);
                Cg[(long long)m * ldc + n] = (TC)vv;
            }
        }
    }
}

// ---------------------------------------------------------------------------
extern "C" void kernel_launch(void* const* d_in, const int* in_sizes, int n_in,
                              void* d_out, int out_size, void* d_ws, size_t ws_size,
                              hipStream_t stream)
{
    const int*   tokens = (const int*)d_in[0];
    const float* masks  = (const float*)d_in[1];
    const int*   ab     = (const int*)d_in[2];
    const float* embed  = (const float*)d_in[3];
    const float* Wq     = (const float*)d_in[4];
    const float* Wk     = (const float*)d_in[5];
    const float* Wv     = (const float*)d_in[6];
    const float* Wo     = (const float*)d_in[7];
    const float* be     = (const float*)d_in[8];
    const float* bs     = (const float*)d_in[9];
    const float* ln_g   = (const float*)d_in[10];
    const float* ln_b   = (const float*)d_in[11];
    const float* ff1w   = (const float*)d_in[12];
    const float* ff1b   = (const float*)d_in[13];
    const float* ff2w   = (const float*)d_in[14];
    const float* ff2b   = (const float*)d_in[15];
    const float* lng    = (const float*)d_in[16];
    const float* lnb    = (const float*)d_in[17];
    float* out = (float*)d_out;

    const long long NX = (long long)BB * TT * DD;          // 4,194,304
    // fp32 region
    float* x     = (float*)d_ws;                           // NX
    float* dense = x + NX;                                 // B*T*T = NX
    float* ks    = dense + NX;                             // B*T*H
    float* alpha = ks + (long long)BB * TT * HH;           // B*H*T*T fp32 (134MB)
    // bf16 region
    bf16_t* h_bf = (bf16_t*)(alpha + (long long)BB * HH * TT * TT);
    bf16_t* q    = h_bf + NX;
    bf16_t* k    = q + NX;
    bf16_t* v    = k + NX;
    bf16_t* vT   = v + NX;
    bf16_t* wT   = vT + NX;                 // per-layer weights: 4*512*512 + 2*512*2048
    bf16_t* wqT  = wT;
    bf16_t* wkT  = wqT + (long long)DD * DD;
    bf16_t* wvT  = wkT + (long long)DD * DD;
    bf16_t* woT  = wvT + (long long)DD * DD;
    bf16_t* ff1T = woT + (long long)DD * DD;               // [F][D]
    bf16_t* ff2T = ff1T + (long long)DD * FFD;             // [D][F]
    bf16_t* ffm  = (bf16_t*)alpha;                         // aliased (FF phase only)
    bf16_t* alpha_bf = (bf16_t*)alpha;                     // in-place rows, lda=1024

    embed_pe_kernel<<<dim3(NX / 256), dim3(256), 0, stream>>>(tokens, embed, x);

    for (int l = 0; l < LNUM; l++) {
        // ---- weight conversion (per layer, into reused buffer) ----
        Ptr4 p4;
        p4.p[0] = Wq + (long long)l * DD * HH * AA;
        p4.p[1] = Wk + (long long)l * DD * HH * AA;
        p4.p[2] = Wv + (long long)l * DD * HH * AA;
        p4.p[3] = Wo + (long long)l * HH * AA * DD;
        wconv4_kernel<<<dim3(8, 8, 4), dim3(256), 0, stream>>>(p4, wqT);
        wconv_kernel<<<dim3(FFD / 64, DD / 64, 1), dim3(256), 0, stream>>>(
            ff1w + (long long)l * DD * FFD, ff1T, DD, FFD);
        wconv_kernel<<<dim3(DD / 64, FFD / 64, 1), dim3(256), 0, stream>>>(
            ff2w + (long long)l * FFD * DD, ff2T, FFD, DD);

        const float* ff1b_l = ff1b + (long long)l * FFD;
        const float* ff2b_l = ff2b + (long long)l * DD;

        // ---- h = LN(x), bf16 ----
        ln_kernel<bf16_t><<<dim3(BB * TT), dim3(256), 0, stream>>>(
            x, h_bf, ln_g + (l * 2 + 0) * DD, ln_b + (l * 2 + 0) * DD);

        // ---- q/k/v = h @ W (bf16 out) ----
        gemm_mfma<128, 128, bf16_t><<<dim3(64, 4, 1), dim3(256), 0, stream>>>(
            h_bf, wqT, q, 512, 512, 512, 512, 1, 0, 0, 0, 0, 0, 0, nullptr, 0, 0);
        gemm_mfma<128, 128, bf16_t><<<dim3(64, 4, 1), dim3(256), 0, stream>>>(
            h_bf, wkT, k, 512, 512, 512, 512, 1, 0, 0, 0, 0, 0, 0, nullptr, 0, 0);
        gemm_mfma<128, 128, bf16_t><<<dim3(64, 4, 1), dim3(256), 0, stream>>>(
            h_bf, wvT, v, 512, 512, 512, 512, 1, 0, 0, 0, 0, 0, 0, nullptr, 0, 0);

        vtrans_kernel<<<dim3(8, BB * HH), dim3(256), 0, stream>>>(v, vT);
        ksum_kernel<<<dim3(BB * TT * HH / 256), dim3(256), 0, stream>>>(k, ks);

        hipMemsetAsync(dense, 0, sizeof(float) * (size_t)BB * TT * TT, stream);
        bias_scatter_kernel<<<dim3((EE + 255) / 256), dim3(256), 0, stream>>>(
            ab, be + (long long)l * BIASDIM * AA, bs + (long long)l * AA, dense);

        // ---- alpha[b,h] = Q[b,:,h,:] @ K[b,:,h,:]^T (fp32 out) ----
        gemm_mfma<128, 128, float><<<dim3(4, 4, BB * HH), dim3(256), 0, stream>>>(
            q, k, alpha, 64, 512, 512, 512,
            HH, (long long)TT * 512, 64LL, (long long)TT * 512, 64LL,
            (long long)HH * TT * TT, (long long)TT * TT, nullptr, 0, 0);

        bias_softmax_kernel<<<dim3(BB * HH * TT), dim3(256), 0, stream>>>(
            alpha, dense, ks, masks);

        // ---- ctx = P @ V: A=alpha_bf (lda=1024), B^T=vT, C=ctx (into h_bf) ----
        gemm_mfma<128, 64, bf16_t><<<dim3(4, 1, BB * HH), dim3(128), 0, stream>>>(
            alpha_bf, vT, h_bf, 512, 1024, 512, 512,
            HH, (long long)HH * TT * 1024, (long long)TT * 1024,
            (long long)HH * AA * TT, (long long)AA * TT,
            (long long)TT * 512, 64LL, nullptr, 0, 0);

        // ---- x += ctx @ Wo (fp32 accum) ----
        gemm_mfma<128, 128, float><<<dim3(64, 4, 1), dim3(256), 0, stream>>>(
            h_bf, woT, x, 512, 512, 512, 512, 1, 0, 0, 0, 0, 0, 0, nullptr, 1, 0);

        // ---- h = LN(x), bf16 ----
        ln_kernel<bf16_t><<<dim3(BB * TT), dim3(256), 0, stream>>>(
            x, h_bf, ln_g + (l * 2 + 1) * DD, ln_b + (l * 2 + 1) * DD);

        // ---- ffm = relu(h @ W1 + b1) (bf16) ----
        gemm_mfma<128, 128, bf16_t><<<dim3(64, 16, 1), dim3(256), 0, stream>>>(
            h_bf, ff1T, ffm, 512, 512, 512, 2048, 1, 0, 0, 0, 0, 0, 0, ff1b_l, 0, 1);

        // ---- x += ffm @ W2 + b2 (fp32 accum) ----
        gemm_mfma<128, 128, float><<<dim3(64, 4, 1), dim3(256), 0, stream>>>(
            ffm, ff2T, x, 2048, 2048, 2048, 512, 1, 0, 0, 0, 0, 0, 0, ff2b_l, 1, 0);
    }

    ln_kernel<float><<<dim3(BB * TT), dim3(256), 0, stream>>>(x, out, lng, lnb);
}

// Round 4
// 1823.654 us; speedup vs baseline: 3.5652x; 1.2784x over previous
//
#include <hip/hip_runtime.h>
#include <hip/hip_bf16.h>

#define LNUM 6
#define BB 16
#define TT 512
#define DD 512
#define HH 8
#define AA 64
#define FFD 2048
#define EE 200000
#define BIASDIM 4
#define ATT_NEG (-3.402823466e38f)

typedef __bf16 bf16_t;
typedef __attribute__((ext_vector_type(8))) __bf16 bf16x8;
typedef __attribute__((ext_vector_type(4))) float f32x4;

typedef __attribute__((address_space(3))) void lds_void;
typedef const __attribute__((address_space(1))) void glb_void;

__device__ __forceinline__ void async_load16(const bf16_t* g, bf16_t* l) {
    __builtin_amdgcn_global_load_lds((glb_void*)g, (lds_void*)l, 16, 0, 0);
}

// ---------------------------------------------------------------------------
// Embedding + positional encoding (fp32 out)
// ---------------------------------------------------------------------------
__global__ __launch_bounds__(256) void embed_pe_kernel(
    const int* __restrict__ tokens, const float* __restrict__ embed,
    float* __restrict__ x)
{
    int idx = blockIdx.x * 256 + threadIdx.x;
    int d  = idx & (DD - 1);
    int bt = idx >> 9;
    int t  = bt & (TT - 1);
    int tok = tokens[bt];
    float e = embed[(long long)tok * DD + d] * 22.62741699796952f; // sqrt(512)
    float p = (float)(2 * (d >> 1)) * (1.0f / (float)DD);
    float denom = exp2f(p * 13.287712379549449f);  // 10000^p
    float angle = (float)t / denom;
    float pe = (d & 1) ? cosf(angle) : sinf(angle);
    x[idx] = e + pe;
}

// ---------------------------------------------------------------------------
// LayerNorm over D=512, fp32 in, TO out
// ---------------------------------------------------------------------------
template <typename TO>
__global__ __launch_bounds__(256) void ln_kernel(
    const float* __restrict__ x, TO* __restrict__ y,
    const float* __restrict__ g, const float* __restrict__ b)
{
    long long row = blockIdx.x;
    const float* xr = x + row * DD;
    int tid = threadIdx.x;
    float v0 = xr[tid], v1 = xr[tid + 256];
    float s = v0 + v1, sq = v0 * v0 + v1 * v1;
#pragma unroll
    for (int o = 32; o > 0; o >>= 1) {
        s  += __shfl_down(s, o);
        sq += __shfl_down(sq, o);
    }
    __shared__ float ss[4], sq4[4];
    if ((tid & 63) == 0) { ss[tid >> 6] = s; sq4[tid >> 6] = sq; }
    __syncthreads();
    float st  = ss[0] + ss[1] + ss[2] + ss[3];
    float sqt = sq4[0] + sq4[1] + sq4[2] + sq4[3];
    float mean = st * (1.0f / DD);
    float var  = sqt * (1.0f / DD) - mean * mean;
    float inv  = rsqrtf(var + 1e-3f);
    y[row * DD + tid]       = (TO)((v0 - mean) * inv * g[tid]       + b[tid]);
    y[row * DD + tid + 256] = (TO)((v1 - mean) * inv * g[tid + 256] + b[tid + 256]);
}

// ---------------------------------------------------------------------------
// ksum[b,t,h] = sum_a k_bf[b,t,h,a]
// ---------------------------------------------------------------------------
__global__ __launch_bounds__(256) void ksum_kernel(
    const bf16_t* __restrict__ k, float* __restrict__ ks)
{
    int idx = blockIdx.x * 256 + threadIdx.x;
    long long base = (long long)idx * AA;
    float s = 0.f;
#pragma unroll
    for (int a = 0; a < AA; a++) s += (float)k[base + a];
    ks[idx] = s;
}

// ---------------------------------------------------------------------------
// Edge-bias scatter
// ---------------------------------------------------------------------------
__global__ __launch_bounds__(256) void bias_scatter_kernel(
    const int* __restrict__ ab, const float* __restrict__ be,
    const float* __restrict__ bs, float* __restrict__ dense)
{
    __shared__ float ev[BIASDIM];
    int tid = threadIdx.x;
    if (tid < BIASDIM) {
        float s = 0.f;
        for (int a = 0; a < AA; a++) s += be[tid * AA + a] * bs[a];
        ev[tid] = s;
    }
    __syncthreads();
    int e = blockIdx.x * 256 + tid;
    if (e < EE) {
        int ty = ab[e * 4 + 0];
        int b  = ab[e * 4 + 1];
        int q  = ab[e * 4 + 2];
        int kk = ab[e * 4 + 3];
        atomicAdd(&dense[((long long)b * TT + q) * TT + kk], ev[ty]);
    }
}

// ---------------------------------------------------------------------------
// Weight convert+transpose: in fp32 [R,Cc] -> out bf16 [Cc,R]. 64x64 tiles.
// ---------------------------------------------------------------------------
__global__ __launch_bounds__(256) void wconv_kernel(
    const float* __restrict__ in, bf16_t* __restrict__ out, int R, int Cc)
{
    __shared__ bf16_t tile[64][65];
    int c0 = blockIdx.x * 64, r0 = blockIdx.y * 64;
    int tid = threadIdx.x;
#pragma unroll
    for (int i = 0; i < 16; i++) {
        int idx = tid + i * 256; int r = idx >> 6, c = idx & 63;
        tile[c][r] = (bf16_t)in[(long long)(r0 + r) * Cc + c0 + c];
    }
    __syncthreads();
#pragma unroll
    for (int i = 0; i < 16; i++) {
        int idx = tid + i * 256; int rr = idx >> 6, cc = idx & 63;
        out[(long long)(c0 + rr) * R + r0 + cc] = tile[rr][cc];
    }
}

struct Ptr4 { const float* p[4]; };

__global__ __launch_bounds__(256) void wconv4_kernel(Ptr4 srcs, bf16_t* __restrict__ out)
{
    __shared__ bf16_t tile[64][65];
    int z = blockIdx.z;
    const float* in = srcs.p[z];
    bf16_t* o = out + (long long)z * DD * DD;
    int c0 = blockIdx.x * 64, r0 = blockIdx.y * 64;
    int tid = threadIdx.x;
#pragma unroll
    for (int i = 0; i < 16; i++) {
        int idx = tid + i * 256; int r = idx >> 6, c = idx & 63;
        tile[c][r] = (bf16_t)in[(long long)(r0 + r) * DD + c0 + c];
    }
    __syncthreads();
#pragma unroll
    for (int i = 0; i < 16; i++) {
        int idx = tid + i * 256; int rr = idx >> 6, cc = idx & 63;
        o[(long long)(c0 + rr) * DD + r0 + cc] = tile[rr][cc];
    }
}

// ---------------------------------------------------------------------------
// v [B,T,H,A] bf16 -> vT [B,H,A,T] bf16
// ---------------------------------------------------------------------------
__global__ __launch_bounds__(256) void vtrans_kernel(
    const bf16_t* __restrict__ v, bf16_t* __restrict__ vT)
{
    __shared__ bf16_t tile[64][65];
    int bh = blockIdx.y; int b = bh >> 3, h = bh & 7;
    int t0 = blockIdx.x * 64;
    int tid = threadIdx.x;
#pragma unroll
    for (int i = 0; i < 16; i++) {
        int idx = tid + i * 256; int r = idx >> 6, c = idx & 63;  // r: t, c: a
        tile[c][r] = v[((long long)(b * TT + t0 + r) * HH + h) * AA + c];
    }
    __syncthreads();
#pragma unroll
    for (int i = 0; i < 16; i++) {
        int idx = tid + i * 256; int a = idx >> 6, t2 = idx & 63;
        vT[(((long long)b * HH + h) * AA + a) * TT + t0 + t2] = tile[a][t2];
    }
}

// ---------------------------------------------------------------------------
// Fused attention: per block = (b,h) x 64 q-rows; 4 waves x 16 q-rows.
// Online softmax over eight 64-token K/V tiles. Alpha never materialized.
//   S = Q K^T (MFMA), bias = dense[q,k]*ksum[k,h], scale 1/8, mask,
//   online softmax (16-lane butterfly in quad-groups), P -> LDS (C->A layout),
//   O += P V (MFMA), final O/l.
// K/V LDS tiles are XOR-swizzled per 16B chunk (slot = c ^ (row&7)) so B-frag
// ds_read_b128 is 2-way-conflict-free; P LDS rows stride 88 bf16 (176 B,
// 16B-aligned, 2-way free).
// ---------------------------------------------------------------------------
__global__ __launch_bounds__(256) void fused_attn_kernel(
    const bf16_t* __restrict__ qg, const bf16_t* __restrict__ kg,
    const bf16_t* __restrict__ vT, const float* __restrict__ dense,
    const float* __restrict__ ksum, const float* __restrict__ masks,
    bf16_t* __restrict__ ctx)
{
    __shared__ __align__(16) bf16_t Ks[64 * 64];
    __shared__ __align__(16) bf16_t Vs[64 * 64];
    __shared__ __align__(16) bf16_t Plds[4 * 16 * 88];

    int tid = threadIdx.x;
    int wave = tid >> 6, lane = tid & 63;
    int row16 = lane & 15, quad = lane >> 4;
    int bh = blockIdx.y; int b = bh >> 3, h = bh & 7;
    int qw = blockIdx.x * 64 + wave * 16;          // wave's q-row base

    // Q fragments: A[m=row16][k=quad*8+j], two K-halves of A=64
    bf16x8 qf[2];
    {
        const bf16_t* qp = qg + (((long long)b * TT + qw + row16) * HH + h) * AA + quad * 8;
        qf[0] = *(const bf16x8*)(qp);
        qf[1] = *(const bf16x8*)(qp + 32);
    }

    f32x4 o[4] = {};
    float m_r[4], l_r[4];
#pragma unroll
    for (int r = 0; r < 4; r++) { m_r[r] = -3.0e38f; l_r[r] = 0.f; }

    bf16_t* Pw = Plds + wave * 16 * 88;
    const float* dbase = dense + (long long)b * TT * TT;
    const float* mbase = masks + (long long)b * TT * TT;

    for (int kt = 0; kt < 8; kt++) {
        int t0 = kt * 64;
#pragma unroll
        for (int p = tid; p < 512; p += 256) {
            int r = p >> 3, s = p & 7, c = s ^ (r & 7);
            async_load16(kg + (((long long)b * TT + t0 + r) * HH + h) * AA + c * 8,
                         Ks + p * 8);
        }
#pragma unroll
        for (int p = tid; p < 512; p += 256) {
            int r = p >> 3, s = p & 7, c = s ^ (r & 7);
            async_load16(vT + ((long long)bh * AA + r) * TT + t0 + c * 8,
                         Vs + p * 8);
        }
        __syncthreads();

        // ---- S = Q @ K^T over this 64-token tile ----
        f32x4 s4[4] = {};
#pragma unroll
        for (int n = 0; n < 4; n++) {
            int row = n * 16 + row16;
            int sw = row & 7;
            bf16x8 kf0 = *(const bf16x8*)(Ks + row * 64 + ((quad ^ sw) * 8));
            bf16x8 kf1 = *(const bf16x8*)(Ks + row * 64 + (((quad + 4) ^ sw) * 8));
            s4[n] = __builtin_amdgcn_mfma_f32_16x16x32_bf16(qf[0], kf0, s4[n], 0, 0, 0);
            s4[n] = __builtin_amdgcn_mfma_f32_16x16x32_bf16(qf[1], kf1, s4[n], 0, 0, 0);
        }

        // ---- bias + scale + mask ----
        float val[4][4];
#pragma unroll
        for (int n = 0; n < 4; n++) {
            int ktok = t0 + n * 16 + row16;
            float ksv = ksum[((long long)b * TT + ktok) * HH + h];
#pragma unroll
            for (int r = 0; r < 4; r++) {
                int qgl = qw + quad * 4 + r;
                float d  = dbase[(long long)qgl * TT + ktok];
                float mk = mbase[(long long)qgl * TT + ktok];
                float vv = 0.125f * fmaf(d, ksv, s4[n][r]);
                val[n][r] = vv * mk + (1.0f - ceilf(mk)) * ATT_NEG;
            }
        }

        // ---- online softmax (rows live in 16-lane quad-groups) ----
        float scl[4];
#pragma unroll
        for (int r = 0; r < 4; r++) {
            float mx = fmaxf(fmaxf(val[0][r], val[1][r]), fmaxf(val[2][r], val[3][r]));
#pragma unroll
            for (int off = 1; off < 16; off <<= 1) mx = fmaxf(mx, __shfl_xor(mx, off));
            float mnew = fmaxf(m_r[r], mx);
            float sc = __expf(m_r[r] - mnew);
            float ps = 0.f;
#pragma unroll
            for (int n = 0; n < 4; n++) {
                float p = __expf(val[n][r] - mnew);
                val[n][r] = p;
                ps += p;
            }
#pragma unroll
            for (int off = 1; off < 16; off <<= 1) ps += __shfl_xor(ps, off);
            l_r[r] = l_r[r] * sc + ps;
            m_r[r] = mnew;
            scl[r] = sc;
        }
#pragma unroll
        for (int j = 0; j < 4; j++)
#pragma unroll
            for (int r = 0; r < 4; r++) o[j][r] *= scl[r];

        // ---- P: C-layout -> A-layout via per-wave LDS ----
#pragma unroll
        for (int n = 0; n < 4; n++)
#pragma unroll
            for (int r = 0; r < 4; r++)
                Pw[(quad * 4 + r) * 88 + n * 16 + row16] = (bf16_t)val[n][r];
        asm volatile("s_waitcnt lgkmcnt(0)" ::: "memory");  // same-wave LDS RAW

        bf16x8 pa0 = *(const bf16x8*)(Pw + row16 * 88 + quad * 8);
        bf16x8 pa1 = *(const bf16x8*)(Pw + row16 * 88 + 32 + quad * 8);
#pragma unroll
        for (int j = 0; j < 4; j++) {
            int row = j * 16 + row16;
            int sw = row & 7;
            bf16x8 vb0 = *(const bf16x8*)(Vs + row * 64 + ((quad ^ sw) * 8));
            bf16x8 vb1 = *(const bf16x8*)(Vs + row * 64 + (((quad + 4) ^ sw) * 8));
            o[j] = __builtin_amdgcn_mfma_f32_16x16x32_bf16(pa0, vb0, o[j], 0, 0, 0);
            o[j] = __builtin_amdgcn_mfma_f32_16x16x32_bf16(pa1, vb1, o[j], 0, 0, 0);
        }
        __syncthreads();
    }

    // ---- normalize + write ctx [B,T,H,A] ----
#pragma unroll
    for (int r = 0; r < 4; r++) {
        float invl = 1.0f / l_r[r];
        int qgl = qw + quad * 4 + r;
        bf16_t* cp = ctx + (((long long)b * TT + qgl) * HH + h) * AA;
#pragma unroll
        for (int j = 0; j < 4; j++)
            cp[j * 16 + row16] = (bf16_t)(o[j][r] * invl);
    }
}

// ---------------------------------------------------------------------------
// MFMA GEMM (m97 structure): C[M,N] (+)= A[M,K] @ B^T[N,K]^T (+bias)(relu)
// ---------------------------------------------------------------------------
template <int BM, int BN, typename TC>
__global__ __launch_bounds__((BM / 64) * (BN / 64) * 64) void gemm_mfma(
    const bf16_t* __restrict__ Ag, const bf16_t* __restrict__ Bg, TC* __restrict__ Cg,
    int K, int lda, int ldb, int ldc,
    const float* __restrict__ bias, int accum, int relu)
{
    constexpr int WN = BN / 64;
    constexpr int NT = (BM / 64) * (BN / 64) * 64;
    __shared__ __align__(16) bf16_t As[BM * 32];
    __shared__ __align__(16) bf16_t Bs[BN * 32];

    int tid = threadIdx.x;
    int wave = tid >> 6, lane = tid & 63;
    int wm = (wave / WN) * 64, wn = (wave % WN) * 64;
    int m0 = blockIdx.x * BM, n0 = blockIdx.y * BN;
    int row16 = lane & 15, quad = lane >> 4;

    f32x4 acc[4][4] = {};

    for (int k0 = 0; k0 < K; k0 += 32) {
#pragma unroll
        for (int p = tid; p < BM * 4; p += NT) {
            int r = p >> 2, c = p & 3;
            async_load16(Ag + (long long)(m0 + r) * lda + k0 + c * 8, As + p * 8);
        }
#pragma unroll
        for (int p = tid; p < BN * 4; p += NT) {
            int r = p >> 2, c = p & 3;
            async_load16(Bg + (long long)(n0 + r) * ldb + k0 + c * 8, Bs + p * 8);
        }
        __syncthreads();
        bf16x8 af[4], bfr[4];
#pragma unroll
        for (int i = 0; i < 4; i++)
            af[i] = *(const bf16x8*)(As + (wm + i * 16 + row16) * 32 + quad * 8);
#pragma unroll
        for (int j = 0; j < 4; j++)
            bfr[j] = *(const bf16x8*)(Bs + (wn + j * 16 + row16) * 32 + quad * 8);
#pragma unroll
        for (int i = 0; i < 4; i++)
#pragma unroll
            for (int j = 0; j < 4; j++)
                acc[i][j] = __builtin_amdgcn_mfma_f32_16x16x32_bf16(
                    af[i], bfr[j], acc[i][j], 0, 0, 0);
        __syncthreads();
    }

#pragma unroll
    for (int i = 0; i < 4; i++) {
#pragma unroll
        for (int j = 0; j < 4; j++) {
#pragma unroll
            for (int r = 0; r < 4; r++) {
                int m = m0 + wm + i * 16 + quad * 4 + r;
                int n = n0 + wn + j * 16 + row16;
                float vv = acc[i][j][r];
                if (bias) vv += bias[n];
                if (accum) vv += (float)Cg[(long long)m * ldc + n];
                if (relu) vv = fmaxf(vv, 0.f);
                Cg[(long long)m * ldc + n] = (TC)vv;
            }
        }
    }
}

// ---------------------------------------------------------------------------
extern "C" void kernel_launch(void* const* d_in, const int* in_sizes, int n_in,
                              void* d_out, int out_size, void* d_ws, size_t ws_size,
                              hipStream_t stream)
{
    const int*   tokens = (const int*)d_in[0];
    const float* masks  = (const float*)d_in[1];
    const int*   ab     = (const int*)d_in[2];
    const float* embed  = (const float*)d_in[3];
    const float* Wq     = (const float*)d_in[4];
    const float* Wk     = (const float*)d_in[5];
    const float* Wv     = (const float*)d_in[6];
    const float* Wo     = (const float*)d_in[7];
    const float* be     = (const float*)d_in[8];
    const float* bs     = (const float*)d_in[9];
    const float* ln_g   = (const float*)d_in[10];
    const float* ln_b   = (const float*)d_in[11];
    const float* ff1w   = (const float*)d_in[12];
    const float* ff1b   = (const float*)d_in[13];
    const float* ff2w   = (const float*)d_in[14];
    const float* ff2b   = (const float*)d_in[15];
    const float* lng    = (const float*)d_in[16];
    const float* lnb    = (const float*)d_in[17];
    float* out = (float*)d_out;

    const long long NX = (long long)BB * TT * DD;          // 4,194,304
    float* x     = (float*)d_ws;                           // NX f32
    float* dense = x + NX;                                 // B*T*T f32
    float* ks    = dense + (long long)BB * TT * TT;        // B*T*H f32
    bf16_t* h_bf = (bf16_t*)(ks + (long long)BB * TT * HH);
    bf16_t* q    = h_bf + NX;
    bf16_t* k    = q + NX;
    bf16_t* v    = k + NX;
    bf16_t* vT   = v + NX;
    bf16_t* wqT  = vT + NX;                                // per-layer weights
    bf16_t* wkT  = wqT + (long long)DD * DD;
    bf16_t* wvT  = wkT + (long long)DD * DD;
    bf16_t* woT  = wvT + (long long)DD * DD;
    bf16_t* ff1T = woT + (long long)DD * DD;               // [F][D]
    bf16_t* ff2T = ff1T + (long long)DD * FFD;             // [D][F]
    bf16_t* ffm  = ff2T + (long long)FFD * DD;             // [B*T, F] bf16

    embed_pe_kernel<<<dim3(NX / 256), dim3(256), 0, stream>>>(tokens, embed, x);

    for (int l = 0; l < LNUM; l++) {
        Ptr4 p4;
        p4.p[0] = Wq + (long long)l * DD * HH * AA;
        p4.p[1] = Wk + (long long)l * DD * HH * AA;
        p4.p[2] = Wv + (long long)l * DD * HH * AA;
        p4.p[3] = Wo + (long long)l * HH * AA * DD;
        wconv4_kernel<<<dim3(8, 8, 4), dim3(256), 0, stream>>>(p4, wqT);
        wconv_kernel<<<dim3(FFD / 64, DD / 64, 1), dim3(256), 0, stream>>>(
            ff1w + (long long)l * DD * FFD, ff1T, DD, FFD);
        wconv_kernel<<<dim3(DD / 64, FFD / 64, 1), dim3(256), 0, stream>>>(
            ff2w + (long long)l * FFD * DD, ff2T, FFD, DD);

        const float* ff1b_l = ff1b + (long long)l * FFD;
        const float* ff2b_l = ff2b + (long long)l * DD;

        ln_kernel<bf16_t><<<dim3(BB * TT), dim3(256), 0, stream>>>(
            x, h_bf, ln_g + (l * 2 + 0) * DD, ln_b + (l * 2 + 0) * DD);

        gemm_mfma<128, 128, bf16_t><<<dim3(64, 4, 1), dim3(256), 0, stream>>>(
            h_bf, wqT, q, 512, 512, 512, 512, nullptr, 0, 0);
        gemm_mfma<128, 128, bf16_t><<<dim3(64, 4, 1), dim3(256), 0, stream>>>(
            h_bf, wkT, k, 512, 512, 512, 512, nullptr, 0, 0);
        gemm_mfma<128, 128, bf16_t><<<dim3(64, 4, 1), dim3(256), 0, stream>>>(
            h_bf, wvT, v, 512, 512, 512, 512, nullptr, 0, 0);

        vtrans_kernel<<<dim3(8, BB * HH), dim3(256), 0, stream>>>(v, vT);
        ksum_kernel<<<dim3(BB * TT * HH / 256), dim3(256), 0, stream>>>(k, ks);

        hipMemsetAsync(dense, 0, sizeof(float) * (size_t)BB * TT * TT, stream);
        bias_scatter_kernel<<<dim3((EE + 255) / 256), dim3(256), 0, stream>>>(
            ab, be + (long long)l * BIASDIM * AA, bs + (long long)l * AA, dense);

        // fused attention: ctx into h_bf
        fused_attn_kernel<<<dim3(TT / 64, BB * HH), dim3(256), 0, stream>>>(
            q, k, vT, dense, ks, masks, h_bf);

        // x += ctx @ Wo
        gemm_mfma<128, 128, float><<<dim3(64, 4, 1), dim3(256), 0, stream>>>(
            h_bf, woT, x, 512, 512, 512, 512, nullptr, 1, 0);

        ln_kernel<bf16_t><<<dim3(BB * TT), dim3(256), 0, stream>>>(
            x, h_bf, ln_g + (l * 2 + 1) * DD, ln_b + (l * 2 + 1) * DD);

        // ffm = relu(h @ W1 + b1)
        gemm_mfma<128, 128, bf16_t><<<dim3(64, 16, 1), dim3(256), 0, stream>>>(
            h_bf, ff1T, ffm, 512, 512, 512, 2048, ff1b_l, 0, 1);

        // x += ffm @ W2 + b2
        gemm_mfma<128, 128, float><<<dim3(64, 4, 1), dim3(256), 0, stream>>>(
            ffm, ff2T, x, 2048, 2048, 2048, 512, ff2b_l, 1, 0);
    }

    ln_kernel<float><<<dim3(BB * TT), dim3(256), 0, stream>>>(x, out, lng, lnb);
}

// Round 6
// 1763.704 us; speedup vs baseline: 3.6863x; 1.0340x over previous
//
#include <hip/hip_runtime.h>
#include <hip/hip_bf16.h>

#define LNUM 6
#define BB 16
#define TT 512
#define DD 512
#define HH 8
#define AA 64
#define FFD 2048
#define EE 200000
#define BIASDIM 4
#define ATT_NEG (-3.402823466e38f)

typedef __bf16 bf16_t;
typedef __attribute__((ext_vector_type(8))) __bf16 bf16x8;
typedef __attribute__((ext_vector_type(4))) float f32x4;

typedef __attribute__((address_space(3))) void lds_void;
typedef const __attribute__((address_space(1))) void glb_void;

__device__ __forceinline__ void async_load16(const bf16_t* g, bf16_t* l) {
    __builtin_amdgcn_global_load_lds((glb_void*)g, (lds_void*)l, 16, 0, 0);
}

// ---------------------------------------------------------------------------
// Embedding + positional encoding (fp32 out)
// ---------------------------------------------------------------------------
__global__ __launch_bounds__(256) void embed_pe_kernel(
    const int* __restrict__ tokens, const float* __restrict__ embed,
    float* __restrict__ x)
{
    int idx = blockIdx.x * 256 + threadIdx.x;
    int d  = idx & (DD - 1);
    int bt = idx >> 9;
    int t  = bt & (TT - 1);
    int tok = tokens[bt];
    float e = embed[(long long)tok * DD + d] * 22.62741699796952f; // sqrt(512)
    float p = (float)(2 * (d >> 1)) * (1.0f / (float)DD);
    float denom = exp2f(p * 13.287712379549449f);  // 10000^p
    float angle = (float)t / denom;
    float pe = (d & 1) ? cosf(angle) : sinf(angle);
    x[idx] = e + pe;
}

// ---------------------------------------------------------------------------
// LayerNorm over D=512, fp32 in, TO out
// ---------------------------------------------------------------------------
template <typename TO>
__global__ __launch_bounds__(256) void ln_kernel(
    const float* __restrict__ x, TO* __restrict__ y,
    const float* __restrict__ g, const float* __restrict__ b)
{
    long long row = blockIdx.x;
    const float* xr = x + row * DD;
    int tid = threadIdx.x;
    float v0 = xr[tid], v1 = xr[tid + 256];
    float s = v0 + v1, sq = v0 * v0 + v1 * v1;
#pragma unroll
    for (int o = 32; o > 0; o >>= 1) {
        s  += __shfl_down(s, o);
        sq += __shfl_down(sq, o);
    }
    __shared__ float ss[4], sq4[4];
    if ((tid & 63) == 0) { ss[tid >> 6] = s; sq4[tid >> 6] = sq; }
    __syncthreads();
    float st  = ss[0] + ss[1] + ss[2] + ss[3];
    float sqt = sq4[0] + sq4[1] + sq4[2] + sq4[3];
    float mean = st * (1.0f / DD);
    float var  = sqt * (1.0f / DD) - mean * mean;
    float inv  = rsqrtf(var + 1e-3f);
    y[row * DD + tid]       = (TO)((v0 - mean) * inv * g[tid]       + b[tid]);
    y[row * DD + tid + 256] = (TO)((v1 - mean) * inv * g[tid + 256] + b[tid + 256]);
}

// ---------------------------------------------------------------------------
// ksum[b,t,h] = sum_a k_bf[b,t,h,a]
// ---------------------------------------------------------------------------
__global__ __launch_bounds__(256) void ksum_kernel(
    const bf16_t* __restrict__ k, float* __restrict__ ks)
{
    int idx = blockIdx.x * 256 + threadIdx.x;
    long long base = (long long)idx * AA;
    float s = 0.f;
#pragma unroll
    for (int a = 0; a < AA; a++) s += (float)k[base + a];
    ks[idx] = s;
}

// ---------------------------------------------------------------------------
// Edge-bias scatter
// ---------------------------------------------------------------------------
__global__ __launch_bounds__(256) void bias_scatter_kernel(
    const int* __restrict__ ab, const float* __restrict__ be,
    const float* __restrict__ bs, float* __restrict__ dense)
{
    __shared__ float ev[BIASDIM];
    int tid = threadIdx.x;
    if (tid < BIASDIM) {
        float s = 0.f;
        for (int a = 0; a < AA; a++) s += be[tid * AA + a] * bs[a];
        ev[tid] = s;
    }
    __syncthreads();
    int e = blockIdx.x * 256 + tid;
    if (e < EE) {
        int ty = ab[e * 4 + 0];
        int b  = ab[e * 4 + 1];
        int q  = ab[e * 4 + 2];
        int kk = ab[e * 4 + 3];
        atomicAdd(&dense[((long long)b * TT + q) * TT + kk], ev[ty]);
    }
}

// ---------------------------------------------------------------------------
// Weight convert+transpose: in fp32 [R,Cc] -> out bf16 [Cc,R]. 64x64 tiles.
// ---------------------------------------------------------------------------
__global__ __launch_bounds__(256) void wconv_kernel(
    const float* __restrict__ in, bf16_t* __restrict__ out, int R, int Cc)
{
    __shared__ bf16_t tile[64][65];
    int c0 = blockIdx.x * 64, r0 = blockIdx.y * 64;
    int tid = threadIdx.x;
#pragma unroll
    for (int i = 0; i < 16; i++) {
        int idx = tid + i * 256; int r = idx >> 6, c = idx & 63;
        tile[c][r] = (bf16_t)in[(long long)(r0 + r) * Cc + c0 + c];
    }
    __syncthreads();
#pragma unroll
    for (int i = 0; i < 16; i++) {
        int idx = tid + i * 256; int rr = idx >> 6, cc = idx & 63;
        out[(long long)(c0 + rr) * R + r0 + cc] = tile[rr][cc];
    }
}

struct Ptr4 { const float* p[4]; };

__global__ __launch_bounds__(256) void wconv4_kernel(Ptr4 srcs, bf16_t* __restrict__ out)
{
    __shared__ bf16_t tile[64][65];
    int z = blockIdx.z;
    const float* in = srcs.p[z];
    bf16_t* o = out + (long long)z * DD * DD;
    int c0 = blockIdx.x * 64, r0 = blockIdx.y * 64;
    int tid = threadIdx.x;
#pragma unroll
    for (int i = 0; i < 16; i++) {
        int idx = tid + i * 256; int r = idx >> 6, c = idx & 63;
        tile[c][r] = (bf16_t)in[(long long)(r0 + r) * DD + c0 + c];
    }
    __syncthreads();
#pragma unroll
    for (int i = 0; i < 16; i++) {
        int idx = tid + i * 256; int rr = idx >> 6, cc = idx & 63;
        o[(long long)(c0 + rr) * DD + r0 + cc] = tile[rr][cc];
    }
}

// ---------------------------------------------------------------------------
// v [B,T,H,A] bf16 -> vT [B,H,A,T] bf16
// ---------------------------------------------------------------------------
__global__ __launch_bounds__(256) void vtrans_kernel(
    const bf16_t* __restrict__ v, bf16_t* __restrict__ vT)
{
    __shared__ bf16_t tile[64][65];
    int bh = blockIdx.y; int b = bh >> 3, h = bh & 7;
    int t0 = blockIdx.x * 64;
    int tid = threadIdx.x;
#pragma unroll
    for (int i = 0; i < 16; i++) {
        int idx = tid + i * 256; int r = idx >> 6, c = idx & 63;  // r: t, c: a
        tile[c][r] = v[((long long)(b * TT + t0 + r) * HH + h) * AA + c];
    }
    __syncthreads();
#pragma unroll
    for (int i = 0; i < 16; i++) {
        int idx = tid + i * 256; int a = idx >> 6, t2 = idx & 63;
        vT[(((long long)b * HH + h) * AA + a) * TT + t0 + t2] = tile[a][t2];
    }
}

// ---------------------------------------------------------------------------
// Fused attention (see R4 comments). Unchanged.
// ---------------------------------------------------------------------------
__global__ __launch_bounds__(256) void fused_attn_kernel(
    const bf16_t* __restrict__ qg, const bf16_t* __restrict__ kg,
    const bf16_t* __restrict__ vT, const float* __restrict__ dense,
    const float* __restrict__ ksum, const float* __restrict__ masks,
    bf16_t* __restrict__ ctx)
{
    __shared__ __align__(16) bf16_t Ks[64 * 64];
    __shared__ __align__(16) bf16_t Vs[64 * 64];
    __shared__ __align__(16) bf16_t Plds[4 * 16 * 88];

    int tid = threadIdx.x;
    int wave = tid >> 6, lane = tid & 63;
    int row16 = lane & 15, quad = lane >> 4;
    int bh = blockIdx.y; int b = bh >> 3, h = bh & 7;
    int qw = blockIdx.x * 64 + wave * 16;

    bf16x8 qf[2];
    {
        const bf16_t* qp = qg + (((long long)b * TT + qw + row16) * HH + h) * AA + quad * 8;
        qf[0] = *(const bf16x8*)(qp);
        qf[1] = *(const bf16x8*)(qp + 32);
    }

    f32x4 o[4] = {};
    float m_r[4], l_r[4];
#pragma unroll
    for (int r = 0; r < 4; r++) { m_r[r] = -3.0e38f; l_r[r] = 0.f; }

    bf16_t* Pw = Plds + wave * 16 * 88;
    const float* dbase = dense + (long long)b * TT * TT;
    const float* mbase = masks + (long long)b * TT * TT;

    for (int kt = 0; kt < 8; kt++) {
        int t0 = kt * 64;
#pragma unroll
        for (int p = tid; p < 512; p += 256) {
            int r = p >> 3, s = p & 7, c = s ^ (r & 7);
            async_load16(kg + (((long long)b * TT + t0 + r) * HH + h) * AA + c * 8,
                         Ks + p * 8);
        }
#pragma unroll
        for (int p = tid; p < 512; p += 256) {
            int r = p >> 3, s = p & 7, c = s ^ (r & 7);
            async_load16(vT + ((long long)bh * AA + r) * TT + t0 + c * 8,
                         Vs + p * 8);
        }
        __syncthreads();

        f32x4 s4[4] = {};
#pragma unroll
        for (int n = 0; n < 4; n++) {
            int row = n * 16 + row16;
            int sw = row & 7;
            bf16x8 kf0 = *(const bf16x8*)(Ks + row * 64 + ((quad ^ sw) * 8));
            bf16x8 kf1 = *(const bf16x8*)(Ks + row * 64 + (((quad + 4) ^ sw) * 8));
            s4[n] = __builtin_amdgcn_mfma_f32_16x16x32_bf16(qf[0], kf0, s4[n], 0, 0, 0);
            s4[n] = __builtin_amdgcn_mfma_f32_16x16x32_bf16(qf[1], kf1, s4[n], 0, 0, 0);
        }

        float val[4][4];
#pragma unroll
        for (int n = 0; n < 4; n++) {
            int ktok = t0 + n * 16 + row16;
            float ksv = ksum[((long long)b * TT + ktok) * HH + h];
#pragma unroll
            for (int r = 0; r < 4; r++) {
                int qgl = qw + quad * 4 + r;
                float d  = dbase[(long long)qgl * TT + ktok];
                float mk = mbase[(long long)qgl * TT + ktok];
                float vv = 0.125f * fmaf(d, ksv, s4[n][r]);
                val[n][r] = vv * mk + (1.0f - ceilf(mk)) * ATT_NEG;
            }
        }

        float scl[4];
#pragma unroll
        for (int r = 0; r < 4; r++) {
            float mx = fmaxf(fmaxf(val[0][r], val[1][r]), fmaxf(val[2][r], val[3][r]));
#pragma unroll
            for (int off = 1; off < 16; off <<= 1) mx = fmaxf(mx, __shfl_xor(mx, off));
            float mnew = fmaxf(m_r[r], mx);
            float sc = __expf(m_r[r] - mnew);
            float ps = 0.f;
#pragma unroll
            for (int n = 0; n < 4; n++) {
                float p = __expf(val[n][r] - mnew);
                val[n][r] = p;
                ps += p;
            }
#pragma unroll
            for (int off = 1; off < 16; off <<= 1) ps += __shfl_xor(ps, off);
            l_r[r] = l_r[r] * sc + ps;
            m_r[r] = mnew;
            scl[r] = sc;
        }
#pragma unroll
        for (int j = 0; j < 4; j++)
#pragma unroll
            for (int r = 0; r < 4; r++) o[j][r] *= scl[r];

#pragma unroll
        for (int n = 0; n < 4; n++)
#pragma unroll
            for (int r = 0; r < 4; r++)
                Pw[(quad * 4 + r) * 88 + n * 16 + row16] = (bf16_t)val[n][r];
        asm volatile("s_waitcnt lgkmcnt(0)" ::: "memory");

        bf16x8 pa0 = *(const bf16x8*)(Pw + row16 * 88 + quad * 8);
        bf16x8 pa1 = *(const bf16x8*)(Pw + row16 * 88 + 32 + quad * 8);
#pragma unroll
        for (int j = 0; j < 4; j++) {
            int row = j * 16 + row16;
            int sw = row & 7;
            bf16x8 vb0 = *(const bf16x8*)(Vs + row * 64 + ((quad ^ sw) * 8));
            bf16x8 vb1 = *(const bf16x8*)(Vs + row * 64 + (((quad + 4) ^ sw) * 8));
            o[j] = __builtin_amdgcn_mfma_f32_16x16x32_bf16(pa0, vb0, o[j], 0, 0, 0);
            o[j] = __builtin_amdgcn_mfma_f32_16x16x32_bf16(pa1, vb1, o[j], 0, 0, 0);
        }
        __syncthreads();
    }

#pragma unroll
    for (int r = 0; r < 4; r++) {
        float invl = 1.0f / l_r[r];
        int qgl = qw + quad * 4 + r;
        bf16_t* cp = ctx + (((long long)b * TT + qgl) * HH + h) * AA;
#pragma unroll
        for (int j = 0; j < 4; j++)
            cp[j * 16 + row16] = (bf16_t)(o[j][r] * invl);
    }
}

// ---------------------------------------------------------------------------
// MFMA GEMM: C[M,N] (+)= A[M,K] @ B^T[N,K]^T (+bias)(relu)
// grid.z batching via per-z element offsets (sAz/sBz/sCz):
//   - multi-matrix batch (QKV): sBz/sCz = matrix strides, full K each.
//   - K-split (ATOMIC=true): sAz/sBz = column offset per chunk, K = chunk len;
//     partials atomicAdd-ed into C (C pre-holds residual), bias added by z==0.
// ---------------------------------------------------------------------------
template <int BM, int BN, typename TC, bool ATOMIC>
__global__ __launch_bounds__((BM / 64) * (BN / 64) * 64) void gemm_mfma(
    const bf16_t* __restrict__ Ag, const bf16_t* __restrict__ Bg, TC* __restrict__ Cg,
    int K, int lda, int ldb, int ldc,
    long long sAz, long long sBz, long long sCz,
    const float* __restrict__ bias, int accum, int relu)
{
    constexpr int WN = BN / 64;
    constexpr int NT = (BM / 64) * (BN / 64) * 64;
    __shared__ __align__(16) bf16_t As[BM * 32];
    __shared__ __align__(16) bf16_t Bs[BN * 32];

    int z = blockIdx.z;
    Ag += z * sAz; Bg += z * sBz; Cg += z * sCz;
    if (ATOMIC && z != 0) bias = nullptr;

    int tid = threadIdx.x;
    int wave = tid >> 6, lane = tid & 63;
    int wm = (wave / WN) * 64, wn = (wave % WN) * 64;
    int m0 = blockIdx.x * BM, n0 = blockIdx.y * BN;
    int row16 = lane & 15, quad = lane >> 4;

    f32x4 acc[4][4] = {};

    for (int k0 = 0; k0 < K; k0 += 32) {
#pragma unroll
        for (int p = tid; p < BM * 4; p += NT) {
            int r = p >> 2, c = p & 3;
            async_load16(Ag + (long long)(m0 + r) * lda + k0 + c * 8, As + p * 8);
        }
#pragma unroll
        for (int p = tid; p < BN * 4; p += NT) {
            int r = p >> 2, c = p & 3;
            async_load16(Bg + (long long)(n0 + r) * ldb + k0 + c * 8, Bs + p * 8);
        }
        __syncthreads();
        bf16x8 af[4], bfr[4];
#pragma unroll
        for (int i = 0; i < 4; i++)
            af[i] = *(const bf16x8*)(As + (wm + i * 16 + row16) * 32 + quad * 8);
#pragma unroll
        for (int j = 0; j < 4; j++)
            bfr[j] = *(const bf16x8*)(Bs + (wn + j * 16 + row16) * 32 + quad * 8);
#pragma unroll
        for (int i = 0; i < 4; i++)
#pragma unroll
            for (int j = 0; j < 4; j++)
                acc[i][j] = __builtin_amdgcn_mfma_f32_16x16x32_bf16(
                    af[i], bfr[j], acc[i][j], 0, 0, 0);
        __syncthreads();
    }

#pragma unroll
    for (int i = 0; i < 4; i++) {
#pragma unroll
        for (int j = 0; j < 4; j++) {
#pragma unroll
            for (int r = 0; r < 4; r++) {
                int m = m0 + wm + i * 16 + quad * 4 + r;
                int n = n0 + wn + j * 16 + row16;
                float vv = acc[i][j][r];
                if (bias) vv += bias[n];
                if (ATOMIC) {
                    atomicAdd((float*)&Cg[(long long)m * ldc + n], vv);
                } else {
                    if (accum) vv += (float)Cg[(long long)m * ldc + n];
                    if (relu) vv = fmaxf(vv, 0.f);
                    Cg[(long long)m * ldc + n] = (TC)vv;
                }
            }
        }
    }
}

// ---------------------------------------------------------------------------
extern "C" void kernel_launch(void* const* d_in, const int* in_sizes, int n_in,
                              void* d_out, int out_size, void* d_ws, size_t ws_size,
                              hipStream_t stream)
{
    const int*   tokens = (const int*)d_in[0];
    const float* masks  = (const float*)d_in[1];
    const int*   ab     = (const int*)d_in[2];
    const float* embed  = (const float*)d_in[3];
    const float* Wq     = (const float*)d_in[4];
    const float* Wk     = (const float*)d_in[5];
    const float* Wv     = (const float*)d_in[6];
    const float* Wo     = (const float*)d_in[7];
    const float* be     = (const float*)d_in[8];
    const float* bs     = (const float*)d_in[9];
    const float* ln_g   = (const float*)d_in[10];
    const float* ln_b   = (const float*)d_in[11];
    const float* ff1w   = (const float*)d_in[12];
    const float* ff1b   = (const float*)d_in[13];
    const float* ff2w   = (const float*)d_in[14];
    const float* ff2b   = (const float*)d_in[15];
    const float* lng    = (const float*)d_in[16];
    const float* lnb    = (const float*)d_in[17];
    float* out = (float*)d_out;

    const long long NX = (long long)BB * TT * DD;          // 4,194,304
    float* x     = (float*)d_ws;                           // NX f32
    float* dense = x + NX;                                 // B*T*T f32
    float* ks    = dense + (long long)BB * TT * TT;        // B*T*H f32
    bf16_t* h_bf = (bf16_t*)(ks + (long long)BB * TT * HH);
    bf16_t* q    = h_bf + NX;
    bf16_t* k    = q + NX;
    bf16_t* v    = k + NX;
    bf16_t* vT   = v + NX;
    bf16_t* wqT  = vT + NX;                                // per-layer weights
    bf16_t* wkT  = wqT + (long long)DD * DD;
    bf16_t* wvT  = wkT + (long long)DD * DD;
    bf16_t* woT  = wvT + (long long)DD * DD;
    bf16_t* ff1T = woT + (long long)DD * DD;               // [F][D]
    bf16_t* ff2T = ff1T + (long long)DD * FFD;             // [D][F]
    bf16_t* ffm  = ff2T + (long long)FFD * DD;             // [B*T, F] bf16

    embed_pe_kernel<<<dim3(NX / 256), dim3(256), 0, stream>>>(tokens, embed, x);

    for (int l = 0; l < LNUM; l++) {
        Ptr4 p4;
        p4.p[0] = Wq + (long long)l * DD * HH * AA;
        p4.p[1] = Wk + (long long)l * DD * HH * AA;
        p4.p[2] = Wv + (long long)l * DD * HH * AA;
        p4.p[3] = Wo + (long long)l * HH * AA * DD;
        wconv4_kernel<<<dim3(8, 8, 4), dim3(256), 0, stream>>>(p4, wqT);
        wconv_kernel<<<dim3(FFD / 64, DD / 64, 1), dim3(256), 0, stream>>>(
            ff1w + (long long)l * DD * FFD, ff1T, DD, FFD);
        wconv_kernel<<<dim3(DD / 64, FFD / 64, 1), dim3(256), 0, stream>>>(
            ff2w + (long long)l * FFD * DD, ff2T, FFD, DD);

        const float* ff1b_l = ff1b + (long long)l * FFD;
        const float* ff2b_l = ff2b + (long long)l * DD;

        ln_kernel<bf16_t><<<dim3(BB * TT), dim3(256), 0, stream>>>(
            x, h_bf, ln_g + (l * 2 + 0) * DD, ln_b + (l * 2 + 0) * DD);

        // q/k/v in ONE launch: z selects weight matrix + output (768 blocks)
        gemm_mfma<128, 128, bf16_t, false><<<dim3(64, 4, 3), dim3(256), 0, stream>>>(
            h_bf, wqT, q, 512, 512, 512, 512,
            0LL, (long long)DD * DD, NX, nullptr, 0, 0);

        vtrans_kernel<<<dim3(8, BB * HH), dim3(256), 0, stream>>>(v, vT);
        ksum_kernel<<<dim3(BB * TT * HH / 256), dim3(256), 0, stream>>>(k, ks);

        hipMemsetAsync(dense, 0, sizeof(float) * (size_t)BB * TT * TT, stream);
        bias_scatter_kernel<<<dim3((EE + 255) / 256), dim3(256), 0, stream>>>(
            ab, be + (long long)l * BIASDIM * AA, bs + (long long)l * AA, dense);

        fused_attn_kernel<<<dim3(TT / 64, BB * HH), dim3(256), 0, stream>>>(
            q, k, vT, dense, ks, masks, h_bf);

        // x += ctx @ Wo  (K-split 2, atomic partials into residual x)
        gemm_mfma<128, 128, float, true><<<dim3(64, 4, 2), dim3(256), 0, stream>>>(
            h_bf, woT, x, 256, 512, 512, 512,
            256LL, 256LL, 0LL, nullptr, 0, 0);

        ln_kernel<bf16_t><<<dim3(BB * TT), dim3(256), 0, stream>>>(
            x, h_bf, ln_g + (l * 2 + 1) * DD, ln_b + (l * 2 + 1) * DD);

        // ffm = relu(h @ W1 + b1)  (1024 blocks already)
        gemm_mfma<128, 128, bf16_t, false><<<dim3(64, 16, 1), dim3(256), 0, stream>>>(
            h_bf, ff1T, ffm, 512, 512, 512, 2048, 0LL, 0LL, 0LL, ff1b_l, 0, 1);

        // x += ffm @ W2 + b2  (K-split 4, atomic partials; bias from z==0)
        gemm_mfma<128, 128, float, true><<<dim3(64, 4, 4), dim3(256), 0, stream>>>(
            ffm, ff2T, x, 512, 2048, 2048, 512,
            512LL, 512LL, 0LL, ff2b_l, 0, 0);
    }

    ln_kernel<float><<<dim3(BB * TT), dim3(256), 0, stream>>>(x, out, lng, lnb);
}

// Round 7
// 1733.907 us; speedup vs baseline: 3.7497x; 1.0172x over previous
//
#include <hip/hip_runtime.h>
#include <hip/hip_bf16.h>

#define LNUM 6
#define BB 16
#define TT 512
#define DD 512
#define HH 8
#define AA 64
#define FFD 2048
#define EE 200000
#define BIASDIM 4
#define ATT_NEG (-3.402823466e38f)

typedef __bf16 bf16_t;
typedef __attribute__((ext_vector_type(8))) __bf16 bf16x8;
typedef __attribute__((ext_vector_type(4))) float f32x4;

typedef __attribute__((address_space(3))) void lds_void;
typedef const __attribute__((address_space(1))) void glb_void;

__device__ __forceinline__ void async_load16(const bf16_t* g, bf16_t* l) {
    __builtin_amdgcn_global_load_lds((glb_void*)g, (lds_void*)l, 16, 0, 0);
}

// ---------------------------------------------------------------------------
// Embedding + positional encoding (fp32 out)
// ---------------------------------------------------------------------------
__global__ __launch_bounds__(256) void embed_pe_kernel(
    const int* __restrict__ tokens, const float* __restrict__ embed,
    float* __restrict__ x)
{
    int idx = blockIdx.x * 256 + threadIdx.x;
    int d  = idx & (DD - 1);
    int bt = idx >> 9;
    int t  = bt & (TT - 1);
    int tok = tokens[bt];
    float e = embed[(long long)tok * DD + d] * 22.62741699796952f; // sqrt(512)
    float p = (float)(2 * (d >> 1)) * (1.0f / (float)DD);
    float denom = exp2f(p * 13.287712379549449f);  // 10000^p
    float angle = (float)t / denom;
    float pe = (d & 1) ? cosf(angle) : sinf(angle);
    x[idx] = e + pe;
}

// ---------------------------------------------------------------------------
// LayerNorm over D=512, fp32 in, TO out
// ---------------------------------------------------------------------------
template <typename TO>
__global__ __launch_bounds__(256) void ln_kernel(
    const float* __restrict__ x, TO* __restrict__ y,
    const float* __restrict__ g, const float* __restrict__ b)
{
    long long row = blockIdx.x;
    const float* xr = x + row * DD;
    int tid = threadIdx.x;
    float v0 = xr[tid], v1 = xr[tid + 256];
    float s = v0 + v1, sq = v0 * v0 + v1 * v1;
#pragma unroll
    for (int o = 32; o > 0; o >>= 1) {
        s  += __shfl_down(s, o);
        sq += __shfl_down(sq, o);
    }
    __shared__ float ss[4], sq4[4];
    if ((tid & 63) == 0) { ss[tid >> 6] = s; sq4[tid >> 6] = sq; }
    __syncthreads();
    float st  = ss[0] + ss[1] + ss[2] + ss[3];
    float sqt = sq4[0] + sq4[1] + sq4[2] + sq4[3];
    float mean = st * (1.0f / DD);
    float var  = sqt * (1.0f / DD) - mean * mean;
    float inv  = rsqrtf(var + 1e-3f);
    y[row * DD + tid]       = (TO)((v0 - mean) * inv * g[tid]       + b[tid]);
    y[row * DD + tid + 256] = (TO)((v1 - mean) * inv * g[tid + 256] + b[tid + 256]);
}

// ---------------------------------------------------------------------------
// ksum[b,t,h] = sum_a k_bf[b,t,h,a]
// ---------------------------------------------------------------------------
__global__ __launch_bounds__(256) void ksum_kernel(
    const bf16_t* __restrict__ k, float* __restrict__ ks)
{
    int idx = blockIdx.x * 256 + threadIdx.x;
    long long base = (long long)idx * AA;
    float s = 0.f;
#pragma unroll
    for (int a = 0; a < AA; a++) s += (float)k[base + a];
    ks[idx] = s;
}

// ---------------------------------------------------------------------------
// Edge-bias scatter
// ---------------------------------------------------------------------------
__global__ __launch_bounds__(256) void bias_scatter_kernel(
    const int* __restrict__ ab, const float* __restrict__ be,
    const float* __restrict__ bs, float* __restrict__ dense)
{
    __shared__ float ev[BIASDIM];
    int tid = threadIdx.x;
    if (tid < BIASDIM) {
        float s = 0.f;
        for (int a = 0; a < AA; a++) s += be[tid * AA + a] * bs[a];
        ev[tid] = s;
    }
    __syncthreads();
    int e = blockIdx.x * 256 + tid;
    if (e < EE) {
        int ty = ab[e * 4 + 0];
        int b  = ab[e * 4 + 1];
        int q  = ab[e * 4 + 2];
        int kk = ab[e * 4 + 3];
        atomicAdd(&dense[((long long)b * TT + q) * TT + kk], ev[ty]);
    }
}

// ---------------------------------------------------------------------------
// Weight convert+transpose: in fp32 [R,Cc] -> out bf16 [Cc,R]. 64x64 tiles.
// ---------------------------------------------------------------------------
__global__ __launch_bounds__(256) void wconv_kernel(
    const float* __restrict__ in, bf16_t* __restrict__ out, int R, int Cc)
{
    __shared__ bf16_t tile[64][65];
    int c0 = blockIdx.x * 64, r0 = blockIdx.y * 64;
    int tid = threadIdx.x;
#pragma unroll
    for (int i = 0; i < 16; i++) {
        int idx = tid + i * 256; int r = idx >> 6, c = idx & 63;
        tile[c][r] = (bf16_t)in[(long long)(r0 + r) * Cc + c0 + c];
    }
    __syncthreads();
#pragma unroll
    for (int i = 0; i < 16; i++) {
        int idx = tid + i * 256; int rr = idx >> 6, cc = idx & 63;
        out[(long long)(c0 + rr) * R + r0 + cc] = tile[rr][cc];
    }
}

struct Ptr4 { const float* p[4]; };

__global__ __launch_bounds__(256) void wconv4_kernel(Ptr4 srcs, bf16_t* __restrict__ out)
{
    __shared__ bf16_t tile[64][65];
    int z = blockIdx.z;
    const float* in = srcs.p[z];
    bf16_t* o = out + (long long)z * DD * DD;
    int c0 = blockIdx.x * 64, r0 = blockIdx.y * 64;
    int tid = threadIdx.x;
#pragma unroll
    for (int i = 0; i < 16; i++) {
        int idx = tid + i * 256; int r = idx >> 6, c = idx & 63;
        tile[c][r] = (bf16_t)in[(long long)(r0 + r) * DD + c0 + c];
    }
    __syncthreads();
#pragma unroll
    for (int i = 0; i < 16; i++) {
        int idx = tid + i * 256; int rr = idx >> 6, cc = idx & 63;
        o[(long long)(c0 + rr) * DD + r0 + cc] = tile[rr][cc];
    }
}

// ---------------------------------------------------------------------------
// v [B,T,H,A] bf16 -> vT [B,H,A,T] bf16
// ---------------------------------------------------------------------------
__global__ __launch_bounds__(256) void vtrans_kernel(
    const bf16_t* __restrict__ v, bf16_t* __restrict__ vT)
{
    __shared__ bf16_t tile[64][65];
    int bh = blockIdx.y; int b = bh >> 3, h = bh & 7;
    int t0 = blockIdx.x * 64;
    int tid = threadIdx.x;
#pragma unroll
    for (int i = 0; i < 16; i++) {
        int idx = tid + i * 256; int r = idx >> 6, c = idx & 63;  // r: t, c: a
        tile[c][r] = v[((long long)(b * TT + t0 + r) * HH + h) * AA + c];
    }
    __syncthreads();
#pragma unroll
    for (int i = 0; i < 16; i++) {
        int idx = tid + i * 256; int a = idx >> 6, t2 = idx & 63;
        vT[(((long long)b * HH + h) * AA + a) * TT + t0 + t2] = tile[a][t2];
    }
}

// ---------------------------------------------------------------------------
// Fused attention (see R4 comments). Unchanged.
// ---------------------------------------------------------------------------
__global__ __launch_bounds__(256) void fused_attn_kernel(
    const bf16_t* __restrict__ qg, const bf16_t* __restrict__ kg,
    const bf16_t* __restrict__ vT, const float* __restrict__ dense,
    const float* __restrict__ ksum, const float* __restrict__ masks,
    bf16_t* __restrict__ ctx)
{
    __shared__ __align__(16) bf16_t Ks[64 * 64];
    __shared__ __align__(16) bf16_t Vs[64 * 64];
    __shared__ __align__(16) bf16_t Plds[4 * 16 * 88];

    int tid = threadIdx.x;
    int wave = tid >> 6, lane = tid & 63;
    int row16 = lane & 15, quad = lane >> 4;
    int bh = blockIdx.y; int b = bh >> 3, h = bh & 7;
    int qw = blockIdx.x * 64 + wave * 16;

    bf16x8 qf[2];
    {
        const bf16_t* qp = qg + (((long long)b * TT + qw + row16) * HH + h) * AA + quad * 8;
        qf[0] = *(const bf16x8*)(qp);
        qf[1] = *(const bf16x8*)(qp + 32);
    }

    f32x4 o[4] = {};
    float m_r[4], l_r[4];
#pragma unroll
    for (int r = 0; r < 4; r++) { m_r[r] = -3.0e38f; l_r[r] = 0.f; }

    bf16_t* Pw = Plds + wave * 16 * 88;
    const float* dbase = dense + (long long)b * TT * TT;
    const float* mbase = masks + (long long)b * TT * TT;

    for (int kt = 0; kt < 8; kt++) {
        int t0 = kt * 64;
#pragma unroll
        for (int p = tid; p < 512; p += 256) {
            int r = p >> 3, s = p & 7, c = s ^ (r & 7);
            async_load16(kg + (((long long)b * TT + t0 + r) * HH + h) * AA + c * 8,
                         Ks + p * 8);
        }
#pragma unroll
        for (int p = tid; p < 512; p += 256) {
            int r = p >> 3, s = p & 7, c = s ^ (r & 7);
            async_load16(vT + ((long long)bh * AA + r) * TT + t0 + c * 8,
                         Vs + p * 8);
        }
        __syncthreads();

        f32x4 s4[4] = {};
#pragma unroll
        for (int n = 0; n < 4; n++) {
            int row = n * 16 + row16;
            int sw = row & 7;
            bf16x8 kf0 = *(const bf16x8*)(Ks + row * 64 + ((quad ^ sw) * 8));
            bf16x8 kf1 = *(const bf16x8*)(Ks + row * 64 + (((quad + 4) ^ sw) * 8));
            s4[n] = __builtin_amdgcn_mfma_f32_16x16x32_bf16(qf[0], kf0, s4[n], 0, 0, 0);
            s4[n] = __builtin_amdgcn_mfma_f32_16x16x32_bf16(qf[1], kf1, s4[n], 0, 0, 0);
        }

        float val[4][4];
#pragma unroll
        for (int n = 0; n < 4; n++) {
            int ktok = t0 + n * 16 + row16;
            float ksv = ksum[((long long)b * TT + ktok) * HH + h];
#pragma unroll
            for (int r = 0; r < 4; r++) {
                int qgl = qw + quad * 4 + r;
                float d  = dbase[(long long)qgl * TT + ktok];
                float mk = mbase[(long long)qgl * TT + ktok];
                float vv = 0.125f * fmaf(d, ksv, s4[n][r]);
                val[n][r] = vv * mk + (1.0f - ceilf(mk)) * ATT_NEG;
            }
        }

        float scl[4];
#pragma unroll
        for (int r = 0; r < 4; r++) {
            float mx = fmaxf(fmaxf(val[0][r], val[1][r]), fmaxf(val[2][r], val[3][r]));
#pragma unroll
            for (int off = 1; off < 16; off <<= 1) mx = fmaxf(mx, __shfl_xor(mx, off));
            float mnew = fmaxf(m_r[r], mx);
            float sc = __expf(m_r[r] - mnew);
            float ps = 0.f;
#pragma unroll
            for (int n = 0; n < 4; n++) {
                float p = __expf(val[n][r] - mnew);
                val[n][r] = p;
                ps += p;
            }
#pragma unroll
            for (int off = 1; off < 16; off <<= 1) ps += __shfl_xor(ps, off);
            l_r[r] = l_r[r] * sc + ps;
            m_r[r] = mnew;
            scl[r] = sc;
        }
#pragma unroll
        for (int j = 0; j < 4; j++)
#pragma unroll
            for (int r = 0; r < 4; r++) o[j][r] *= scl[r];

#pragma unroll
        for (int n = 0; n < 4; n++)
#pragma unroll
            for (int r = 0; r < 4; r++)
                Pw[(quad * 4 + r) * 88 + n * 16 + row16] = (bf16_t)val[n][r];
        asm volatile("s_waitcnt lgkmcnt(0)" ::: "memory");

        bf16x8 pa0 = *(const bf16x8*)(Pw + row16 * 88 + quad * 8);
        bf16x8 pa1 = *(const bf16x8*)(Pw + row16 * 88 + 32 + quad * 8);
#pragma unroll
        for (int j = 0; j < 4; j++) {
            int row = j * 16 + row16;
            int sw = row & 7;
            bf16x8 vb0 = *(const bf16x8*)(Vs + row * 64 + ((quad ^ sw) * 8));
            bf16x8 vb1 = *(const bf16x8*)(Vs + row * 64 + (((quad + 4) ^ sw) * 8));
            o[j] = __builtin_amdgcn_mfma_f32_16x16x32_bf16(pa0, vb0, o[j], 0, 0, 0);
            o[j] = __builtin_amdgcn_mfma_f32_16x16x32_bf16(pa1, vb1, o[j], 0, 0, 0);
        }
        __syncthreads();
    }

#pragma unroll
    for (int r = 0; r < 4; r++) {
        float invl = 1.0f / l_r[r];
        int qgl = qw + quad * 4 + r;
        bf16_t* cp = ctx + (((long long)b * TT + qgl) * HH + h) * AA;
#pragma unroll
        for (int j = 0; j < 4; j++)
            cp[j * 16 + row16] = (bf16_t)(o[j][r] * invl);
    }
}

// ---------------------------------------------------------------------------
// MFMA GEMM, double-buffered: C[M,N] (+)= A[M,K] @ B^T[N,K]^T (+bias)(relu)
// Ping-pong LDS: one barrier per K-iter; next tile's global_load_lds issue
// right after the barrier and stay in flight across the whole compute phase
// (they drain at the NEXT barrier). Safe: barrier at iter i guarantees all
// waves consumed buf(i-1) (lgkm drained), so restaging it is race-free.
// grid.z batching via per-z element offsets (multi-matrix QKV: z=3).
// ---------------------------------------------------------------------------
template <int BM, int BN, typename TC>
__global__ __launch_bounds__((BM / 64) * (BN / 64) * 64) void gemm_mfma(
    const bf16_t* __restrict__ Ag, const bf16_t* __restrict__ Bg, TC* __restrict__ Cg,
    int K, int lda, int ldb, int ldc,
    long long sAz, long long sBz, long long sCz,
    const float* __restrict__ bias, int accum, int relu)
{
    constexpr int WN = BN / 64;
    constexpr int NT = (BM / 64) * (BN / 64) * 64;
    __shared__ __align__(16) bf16_t As[2][BM * 32];
    __shared__ __align__(16) bf16_t Bs[2][BN * 32];

    int z = blockIdx.z;
    Ag += z * sAz; Bg += z * sBz; Cg += z * sCz;

    int tid = threadIdx.x;
    int wave = tid >> 6, lane = tid & 63;
    int wm = (wave / WN) * 64, wn = (wave % WN) * 64;
    int m0 = blockIdx.x * BM, n0 = blockIdx.y * BN;
    int row16 = lane & 15, quad = lane >> 4;

    f32x4 acc[4][4] = {};

    // prologue: stage k0=0 into buf 0
#pragma unroll
    for (int p = tid; p < BM * 4; p += NT) {
        int r = p >> 2, c = p & 3;
        async_load16(Ag + (long long)(m0 + r) * lda + c * 8, As[0] + p * 8);
    }
#pragma unroll
    for (int p = tid; p < BN * 4; p += NT) {
        int r = p >> 2, c = p & 3;
        async_load16(Bg + (long long)(n0 + r) * ldb + c * 8, Bs[0] + p * 8);
    }

    int ib = 0;
    for (int k0 = 0; k0 < K; k0 += 32, ib ^= 1) {
        __syncthreads();               // drains buf[ib] loads (vmcnt 0)
        if (k0 + 32 < K) {             // prefetch next tile into alt buffer
            int kn = k0 + 32;
#pragma unroll
            for (int p = tid; p < BM * 4; p += NT) {
                int r = p >> 2, c = p & 3;
                async_load16(Ag + (long long)(m0 + r) * lda + kn + c * 8,
                             As[ib ^ 1] + p * 8);
            }
#pragma unroll
            for (int p = tid; p < BN * 4; p += NT) {
                int r = p >> 2, c = p & 3;
                async_load16(Bg + (long long)(n0 + r) * ldb + kn + c * 8,
                             Bs[ib ^ 1] + p * 8);
            }
        }
        bf16x8 af[4], bfr[4];
#pragma unroll
        for (int i = 0; i < 4; i++)
            af[i] = *(const bf16x8*)(As[ib] + (wm + i * 16 + row16) * 32 + quad * 8);
#pragma unroll
        for (int j = 0; j < 4; j++)
            bfr[j] = *(const bf16x8*)(Bs[ib] + (wn + j * 16 + row16) * 32 + quad * 8);
#pragma unroll
        for (int i = 0; i < 4; i++)
#pragma unroll
            for (int j = 0; j < 4; j++)
                acc[i][j] = __builtin_amdgcn_mfma_f32_16x16x32_bf16(
                    af[i], bfr[j], acc[i][j], 0, 0, 0);
    }

#pragma unroll
    for (int i = 0; i < 4; i++) {
#pragma unroll
        for (int j = 0; j < 4; j++) {
#pragma unroll
            for (int r = 0; r < 4; r++) {
                int m = m0 + wm + i * 16 + quad * 4 + r;
                int n = n0 + wn + j * 16 + row16;
                float vv = acc[i][j][r];
                if (bias) vv += bias[n];
                if (accum) vv += (float)Cg[(long long)m * ldc + n];
                if (relu) vv = fmaxf(vv, 0.f);
                Cg[(long long)m * ldc + n] = (TC)vv;
            }
        }
    }
}

// ---------------------------------------------------------------------------
extern "C" void kernel_launch(void* const* d_in, const int* in_sizes, int n_in,
                              void* d_out, int out_size, void* d_ws, size_t ws_size,
                              hipStream_t stream)
{
    const int*   tokens = (const int*)d_in[0];
    const float* masks  = (const float*)d_in[1];
    const int*   ab     = (const int*)d_in[2];
    const float* embed  = (const float*)d_in[3];
    const float* Wq     = (const float*)d_in[4];
    const float* Wk     = (const float*)d_in[5];
    const float* Wv     = (const float*)d_in[6];
    const float* Wo     = (const float*)d_in[7];
    const float* be     = (const float*)d_in[8];
    const float* bs     = (const float*)d_in[9];
    const float* ln_g   = (const float*)d_in[10];
    const float* ln_b   = (const float*)d_in[11];
    const float* ff1w   = (const float*)d_in[12];
    const float* ff1b   = (const float*)d_in[13];
    const float* ff2w   = (const float*)d_in[14];
    const float* ff2b   = (const float*)d_in[15];
    const float* lng    = (const float*)d_in[16];
    const float* lnb    = (const float*)d_in[17];
    float* out = (float*)d_out;

    const long long NX = (long long)BB * TT * DD;          // 4,194,304
    float* x     = (float*)d_ws;                           // NX f32
    float* dense = x + NX;                                 // B*T*T f32
    float* ks    = dense + (long long)BB * TT * TT;        // B*T*H f32
    bf16_t* h_bf = (bf16_t*)(ks + (long long)BB * TT * HH);
    bf16_t* q    = h_bf + NX;
    bf16_t* k    = q + NX;
    bf16_t* v    = k + NX;
    bf16_t* vT   = v + NX;
    bf16_t* wqT  = vT + NX;                                // per-layer weights
    bf16_t* wkT  = wqT + (long long)DD * DD;
    bf16_t* wvT  = wkT + (long long)DD * DD;
    bf16_t* woT  = wvT + (long long)DD * DD;
    bf16_t* ff1T = woT + (long long)DD * DD;               // [F][D]
    bf16_t* ff2T = ff1T + (long long)DD * FFD;             // [D][F]
    bf16_t* ffm  = ff2T + (long long)FFD * DD;             // [B*T, F] bf16

    embed_pe_kernel<<<dim3(NX / 256), dim3(256), 0, stream>>>(tokens, embed, x);

    for (int l = 0; l < LNUM; l++) {
        Ptr4 p4;
        p4.p[0] = Wq + (long long)l * DD * HH * AA;
        p4.p[1] = Wk + (long long)l * DD * HH * AA;
        p4.p[2] = Wv + (long long)l * DD * HH * AA;
        p4.p[3] = Wo + (long long)l * HH * AA * DD;
        wconv4_kernel<<<dim3(8, 8, 4), dim3(256), 0, stream>>>(p4, wqT);
        wconv_kernel<<<dim3(FFD / 64, DD / 64, 1), dim3(256), 0, stream>>>(
            ff1w + (long long)l * DD * FFD, ff1T, DD, FFD);
        wconv_kernel<<<dim3(DD / 64, FFD / 64, 1), dim3(256), 0, stream>>>(
            ff2w + (long long)l * FFD * DD, ff2T, FFD, DD);

        const float* ff1b_l = ff1b + (long long)l * FFD;
        const float* ff2b_l = ff2b + (long long)l * DD;

        ln_kernel<bf16_t><<<dim3(BB * TT), dim3(256), 0, stream>>>(
            x, h_bf, ln_g + (l * 2 + 0) * DD, ln_b + (l * 2 + 0) * DD);

        // q/k/v in ONE launch (768 blocks, 3/CU, dbuf)
        gemm_mfma<128, 128, bf16_t><<<dim3(64, 4, 3), dim3(256), 0, stream>>>(
            h_bf, wqT, q, 512, 512, 512, 512,
            0LL, (long long)DD * DD, NX, nullptr, 0, 0);

        vtrans_kernel<<<dim3(8, BB * HH), dim3(256), 0, stream>>>(v, vT);
        ksum_kernel<<<dim3(BB * TT * HH / 256), dim3(256), 0, stream>>>(k, ks);

        hipMemsetAsync(dense, 0, sizeof(float) * (size_t)BB * TT * TT, stream);
        bias_scatter_kernel<<<dim3((EE + 255) / 256), dim3(256), 0, stream>>>(
            ab, be + (long long)l * BIASDIM * AA, bs + (long long)l * AA, dense);

        fused_attn_kernel<<<dim3(TT / 64, BB * HH), dim3(256), 0, stream>>>(
            q, k, vT, dense, ks, masks, h_bf);

        // x += ctx @ Wo  (128x64 tile: 512 blocks, 2/CU, streaming accum)
        gemm_mfma<128, 64, float><<<dim3(64, 8, 1), dim3(128), 0, stream>>>(
            h_bf, woT, x, 512, 512, 512, 512,
            0LL, 0LL, 0LL, nullptr, 1, 0);

        ln_kernel<bf16_t><<<dim3(BB * TT), dim3(256), 0, stream>>>(
            x, h_bf, ln_g + (l * 2 + 1) * DD, ln_b + (l * 2 + 1) * DD);

        // ffm = relu(h @ W1 + b1)  (1024 blocks, dbuf)
        gemm_mfma<128, 128, bf16_t><<<dim3(64, 16, 1), dim3(256), 0, stream>>>(
            h_bf, ff1T, ffm, 512, 512, 512, 2048, 0LL, 0LL, 0LL, ff1b_l, 0, 1);

        // x += ffm @ W2 + b2  (128x64 tile: 512 blocks, 2/CU, streaming accum)
        gemm_mfma<128, 64, float><<<dim3(64, 8, 1), dim3(128), 0, stream>>>(
            ffm, ff2T, x, 2048, 2048, 2048, 512,
            0LL, 0LL, 0LL, ff2b_l, 1, 0);
    }

    ln_kernel<float><<<dim3(BB * TT), dim3(256), 0, stream>>>(x, out, lng, lnb);
}